// Round 16
// baseline (268.709 us; speedup 1.0000x reference)
//
#include <hip/hip_runtime.h>
#include <hip/hip_bf16.h>
#include <math.h>

constexpr int NTOT = 65536;
constexpr int D    = 128;
constexpr int BG   = 256;
constexpr int E0 = 131072, E1 = 104960, E2 = 83968;
constexpr int EG0 = 512;
constexpr int KP0 = 410, KP1 = 328;

typedef __bf16 bf16x8 __attribute__((ext_vector_type(8)));
typedef __bf16 bf16x4 __attribute__((ext_vector_type(4)));
typedef __bf16 bf16x2 __attribute__((ext_vector_type(2)));
typedef float  f32x4  __attribute__((ext_vector_type(4)));

__device__ __forceinline__ float2 tof2(bf16x2 v) {
  return make_float2((float)v[0], (float)v[1]);
}
__device__ __forceinline__ bf16x2 tob2(float ax, float ay) {
  bf16x2 r; r[0] = (__bf16)ax; r[1] = (__bf16)ay; return r;
}

// ---------- embeddings (f32 tables -> bf16 activations) ----------
__global__ __launch_bounds__(256) void k_embed_x(const int* __restrict__ xi,
                                                 const float* __restrict__ tab,
                                                 __bf16* __restrict__ x) {
  int t = blockIdx.x * 256 + threadIdx.x;      // NTOT*32 threads
  int v = t >> 5, q = (t & 31) << 2;
  float4 s = {0.f, 0.f, 0.f, 0.f};
#pragma unroll
  for (int j = 0; j < 9; ++j) {
    int r = xi[v * 9 + j];
    float4 a = *(const float4*)&tab[r * D + q];
    s.x += a.x; s.y += a.y; s.z += a.z; s.w += a.w;
  }
  bf16x4 o; o[0] = (__bf16)s.x; o[1] = (__bf16)s.y; o[2] = (__bf16)s.z; o[3] = (__bf16)s.w;
  *(bf16x4*)&x[(size_t)v * D + q] = o;
}

__global__ __launch_bounds__(256) void k_embed_e(const int* __restrict__ bi,
                                                 const float* __restrict__ tab,
                                                 __bf16* __restrict__ e) {
  int t = blockIdx.x * 256 + threadIdx.x;      // E0*32 threads
  int i = t >> 5, q = (t & 31) << 2;
  float4 s = {0.f, 0.f, 0.f, 0.f};
#pragma unroll
  for (int j = 0; j < 3; ++j) {
    int r = bi[i * 3 + j];
    float4 a = *(const float4*)&tab[r * D + q];
    s.x += a.x; s.y += a.y; s.z += a.z; s.w += a.w;
  }
  bf16x4 o; o[0] = (__bf16)s.x; o[1] = (__bf16)s.y; o[2] = (__bf16)s.z; o[3] = (__bf16)s.w;
  *(bf16x4*)&e[(size_t)i * D + q] = o;
}

// ---------- bf16 MFMA GEMM (for z = e @ W_hyp): C = A @ W, A/C bf16 ----------
__global__ __launch_bounds__(256) void k_gemm_bf16(const __bf16* __restrict__ A,
                                                   const float* __restrict__ W,
                                                   const float* __restrict__ bias,
                                                   __bf16* __restrict__ C) {
  __shared__ bf16x8 Wl[4][8][64];              // [ks][nt][lane] fragments, 32 KB
  const int t = threadIdx.x, w = t >> 6, lane = t & 63;
  const int m0 = blockIdx.x * 128;

  bf16x8* Wf = (bf16x8*)Wl;
  for (int q = t; q < 2048; q += 256) {
    int ks = q >> 9, nt = (q >> 6) & 7, l = q & 63;
    int kk = ks * 32 + ((l >> 4) << 3);
    int nn = nt * 16 + (l & 15);
    const float* wp = W + (size_t)kk * 128 + nn;
    bf16x8 v;
#pragma unroll
    for (int b = 0; b < 8; ++b) v[b] = (__bf16)wp[(size_t)b * 128];
    Wf[q] = v;
  }

  const int r0 = m0 + w * 32 + (lane & 15);
  const __bf16* Ap0 = A + (size_t)r0 * 128 + ((lane >> 4) << 3);
  const __bf16* Ap1 = Ap0 + 16 * 128;
  bf16x8 a0[4], a1[4];
#pragma unroll
  for (int ks = 0; ks < 4; ++ks) {
    a0[ks] = *(const bf16x8*)(Ap0 + ks * 32);
    a1[ks] = *(const bf16x8*)(Ap1 + ks * 32);
  }
  __syncthreads();

  f32x4 acc0[8] = {}; f32x4 acc1[8] = {};
#pragma unroll
  for (int ks = 0; ks < 4; ++ks) {
#pragma unroll
    for (int nt = 0; nt < 8; ++nt) {
      bf16x8 b = Wl[ks][nt][lane];
      acc0[nt] = __builtin_amdgcn_mfma_f32_16x16x32_bf16(a0[ks], b, acc0[nt], 0, 0, 0);
      acc1[nt] = __builtin_amdgcn_mfma_f32_16x16x32_bf16(a1[ks], b, acc1[nt], 0, 0, 0);
    }
  }

  const int orow = m0 + w * 32 + ((lane >> 4) << 2);
  const int ocol = lane & 15;
#pragma unroll
  for (int nt = 0; nt < 8; ++nt) {
    float bb = bias ? bias[nt * 16 + ocol] : 0.f;
    __bf16* cp = C + (size_t)orow * 128 + nt * 16 + ocol;
#pragma unroll
    for (int r = 0; r < 4; ++r) {
      cp[(size_t)r * 128]        = (__bf16)(acc0[nt][r] + bb);
      cp[(size_t)(16 + r) * 128] = (__bf16)(acc1[nt][r] + bb);
    }
  }
}

// ---------- MEGA GCN layer: fused h = x@Wg + b (MFMA into LDS) + CSR message
//            passing + finalize + in-place x update + readout.
//            1 block/graph, 1024 thr (16 waves x 16 rows). ----------
template <int EG, bool HAS_EW>
__global__ __launch_bounds__(1024, 4) void k_gcn_fused(const int* __restrict__ ei, int E,
                                                       const __bf16* __restrict__ e,
                                                       const float* __restrict__ Wg,
                                                       const float* __restrict__ bg,
                                                       const float* __restrict__ ew,
                                                       const float* __restrict__ root,
                                                       __bf16* __restrict__ x,
                                                       float* __restrict__ xs) {
  constexpr int NW = 16;
  __shared__ bf16x8 Wl[4][8][64];             // 32 KB W fragments
  __shared__ __bf16 hl[256 * 128];            // 64 KB h tile
  __shared__ int   pke[EG];
  __shared__ float coef[EG];
  __shared__ int   cnts[256];
  __shared__ int   cntd[256];
  __shared__ int   off[257];
  __shared__ int   cur[256];
  __shared__ short adj[EG];
  __shared__ float redm[16 * 128], reds[16 * 128];   // 16 KB
  const int g = blockIdx.x;
  const int t = threadIdx.x, w = t >> 6, lane = t & 63;
  const bf16x2* eg2 = (const bf16x2*)e + (size_t)g * EG * 64 + lane;
  bf16x2* xg2 = (bf16x2*)x + (size_t)g * 256 * 64 + lane;

  if (t < 256) { cnts[t] = 0; cntd[t] = 0; }
  __syncthreads();

  // Phase 1: CSR counts + packed indices, and W fragment staging (independent)
  for (int j = t; j < EG; j += 1024) {
    int s = ei[g * EG + j] & 255, d = ei[E + g * EG + j] & 255;
    pke[j] = s | (d << 8);
    atomicAdd(&cnts[s], 1);
    atomicAdd(&cntd[d], 1);
  }
  {
    bf16x8* Wf = (bf16x8*)Wl;
    for (int q = t; q < 2048; q += 1024) {
      int ks = q >> 9, nt = (q >> 6) & 7, l = q & 63;
      int kk = ks * 32 + ((l >> 4) << 3);
      int nn = nt * 16 + (l & 15);
      const float* wp = Wg + (size_t)kk * 128 + nn;
      bf16x8 v;
#pragma unroll
      for (int b = 0; b < 8; ++b) v[b] = (__bf16)wp[(size_t)b * 128];
      Wf[q] = v;
    }
  }
  __syncthreads();

  // Phase 2a: MFMA h = x@Wg + bg for this graph's 256 rows -> LDS hl
  {
    const int r0 = w * 16 + (lane & 15);
    const __bf16* Ap = x + ((size_t)(g * 256 + r0)) * 128 + ((lane >> 4) << 3);
    bf16x8 af[4];
#pragma unroll
    for (int ks = 0; ks < 4; ++ks) af[ks] = *(const bf16x8*)(Ap + ks * 32);
    f32x4 acc[8] = {};
#pragma unroll
    for (int ks = 0; ks < 4; ++ks) {
#pragma unroll
      for (int nt = 0; nt < 8; ++nt) {
        acc[nt] = __builtin_amdgcn_mfma_f32_16x16x32_bf16(af[ks], Wl[ks][nt][lane], acc[nt], 0, 0, 0);
      }
    }
    const int lrow = w * 16 + ((lane >> 4) << 2);
    const int ocol = lane & 15;
#pragma unroll
    for (int nt = 0; nt < 8; ++nt) {
      float bb = bg[nt * 16 + ocol];
#pragma unroll
      for (int r = 0; r < 4; ++r)
        hl[(lrow + r) * 128 + nt * 16 + ocol] = (__bf16)(acc[nt][r] + bb);
    }
  }

  // Phase 2b: per-edge coefficient
  for (int j = t; j < EG; j += 1024) {
    int p = pke[j];
    int s = p & 255, d = (p >> 8) & 255;
    float c = rsqrtf(((float)cnts[s] + 1.f) * ((float)cnts[d] + 1.f));
    if (HAS_EW) c *= ew[g * EG + j];
    coef[j] = c;
  }

  // Phase 2c: exclusive scan of cntd
  if (t < 256) off[t + 1] = cntd[t];
  if (t == 0) off[0] = 0;
  __syncthreads();
  for (int st = 1; st < 256; st <<= 1) {
    int add = 0;
    if (t < 256 && t + 1 > st) add = off[t + 1 - st];
    __syncthreads();
    if (t < 256) off[t + 1] += add;
    __syncthreads();
  }
  if (t < 256) cur[t] = off[t];
  __syncthreads();

  for (int j = t; j < EG; j += 1024) {
    int d = (pke[j] >> 8) & 255;
    int pos = atomicAdd(&cur[d], 1);
    adj[pos] = (short)j;
  }
  __syncthreads();

  // Phase 3: per-node accumulate (e global, h LDS) + finalize + x + readout
  const float rvx = root[2 * lane], rvy = root[2 * lane + 1];
  float2 mx = {-1e30f, -1e30f}, sm = {0.f, 0.f};
  for (int n = w; n < 256; n += NW) {
    float2 val = {0.f, 0.f};
    int b0 = off[n], b1 = off[n + 1];
    int k = b0;
    for (; k + 1 < b1; k += 2) {
      int j0 = adj[k], j1 = adj[k + 1];
      int s0 = pke[j0] & 255, s1 = pke[j1] & 255;
      float2 e0 = tof2(eg2[(size_t)j0 * 64]), e1 = tof2(eg2[(size_t)j1 * 64]);
      float2 h0 = tof2(*(const bf16x2*)&hl[s0 * 128 + 2 * lane]);
      float2 h1 = tof2(*(const bf16x2*)&hl[s1 * 128 + 2 * lane]);
      float c0 = coef[j0], c1 = coef[j1];
      val.x += c0 * fmaxf(h0.x + e0.x, 0.f) + c1 * fmaxf(h1.x + e1.x, 0.f);
      val.y += c0 * fmaxf(h0.y + e0.y, 0.f) + c1 * fmaxf(h1.y + e1.y, 0.f);
    }
    if (k < b1) {
      int j0 = adj[k];
      int s0 = pke[j0] & 255;
      float2 e0 = tof2(eg2[(size_t)j0 * 64]);
      float2 h0 = tof2(*(const bf16x2*)&hl[s0 * 128 + 2 * lane]);
      float c0 = coef[j0];
      val.x += c0 * fmaxf(h0.x + e0.x, 0.f);
      val.y += c0 * fmaxf(h0.y + e0.y, 0.f);
    }
    float inv = 1.f / ((float)cnts[n] + 1.f);
    float2 hv = tof2(*(const bf16x2*)&hl[n * 128 + 2 * lane]);
    float xvx = fmaxf(val.x + fmaxf(hv.x + rvx, 0.f) * inv, 0.f);
    float xvy = fmaxf(val.y + fmaxf(hv.y + rvy, 0.f) * inv, 0.f);
    xg2[(size_t)n * 64] = tob2(xvx, xvy);
    mx.x = fmaxf(mx.x, xvx); mx.y = fmaxf(mx.y, xvy);
    sm.x += xvx;             sm.y += xvy;
  }
  redm[w * 128 + 2 * lane]     = mx.x;
  redm[w * 128 + 2 * lane + 1] = mx.y;
  reds[w * 128 + 2 * lane]     = sm.x;
  reds[w * 128 + 2 * lane + 1] = sm.y;
  __syncthreads();

  if (t < 128) {
    float M = redm[t], S2 = reds[t];
#pragma unroll
    for (int k = 1; k < 16; ++k) {
      M = fmaxf(M, redm[k * 128 + t]);
      S2 += reds[k * 128 + t];
    }
    xs[g * 384 + t]       += M;
    xs[g * 384 + 128 + t] += S2 * (1.f / 256.f);
    xs[g * 384 + 256 + t] += S2;
  }
}

// ---------- fused hyperconv: 1 block/graph, 1024 thr, bf16x2/lane.
//            S in LDS as bf16 (64 KB; f32 register accumulation).
//            LDS ~77 KB -> 2 blocks/CU. CSR + gather + eout + score dot. ----------
template <int EG>
__global__ __launch_bounds__(1024, 8) void k_hyper_fused(const int* __restrict__ ei, int E,
                                                         const __bf16* __restrict__ z,
                                                         const float* __restrict__ bias,
                                                         const float* __restrict__ wsc,
                                                         __bf16* __restrict__ eout,
                                                         float* __restrict__ zs) {
  constexpr int NW = 16;
  __shared__ __bf16 S[256 * 128];             // 64 KB (bf16)
  __shared__ int   pke[EG];
  __shared__ float as_[EG], ad_[EG], az_[EG];
  __shared__ int   cnt[256];
  __shared__ int   off[257];
  __shared__ int   cur[256];
  __shared__ short adj[2 * EG];
  const int g = blockIdx.x;
  const int t = threadIdx.x, w = t >> 6, lane = t & 63;
  const bf16x2* zg2 = (const bf16x2*)z + (size_t)g * EG * 64 + lane;
  bf16x2* eo2 = (bf16x2*)eout + (size_t)g * EG * 64 + lane;
  bf16x2* S2 = (bf16x2*)S;

  if (t < 256) cnt[t] = 0;
  __syncthreads();

  for (int j = t; j < EG; j += 1024) {
    int s = ei[g * EG + j] & 255, d = ei[E + g * EG + j] & 255;
    pke[j] = s | (d << 8);
    atomicAdd(&cnt[s], 1);
    atomicAdd(&cnt[d], 1);
  }
  __syncthreads();

  // per-edge gather constants
  for (int j = t; j < EG; j += 1024) {
    int p = pke[j];
    int s = p & 255, d = (p >> 8) & 255;
    int cs = cnt[s], cd = cnt[d];
    float bis  = (cs != 1) ? 1.f / (float)cs : 0.f;
    float bid_ = (cd != 1) ? 1.f / (float)cd : 0.f;
    float dinv = 1.f / (1.f + (cs != 1 ? 1.f : 0.f) + (cd != 1 ? 1.f : 0.f));
    as_[j] = dinv * bis;
    ad_[j] = dinv * bid_;
    az_[j] = dinv;
  }

  if (t < 256) off[t + 1] = cnt[t];
  if (t == 0) off[0] = 0;
  __syncthreads();
  for (int st = 1; st < 256; st <<= 1) {
    int add = 0;
    if (t < 256 && t + 1 > st) add = off[t + 1 - st];
    __syncthreads();
    if (t < 256) off[t + 1] += add;
    __syncthreads();
  }
  if (t < 256) cur[t] = off[t];
  __syncthreads();

  for (int j = t; j < EG; j += 1024) {
    int p = pke[j];
    int pos0 = atomicAdd(&cur[p & 255], 1);
    adj[pos0] = (short)j;
    int pos1 = atomicAdd(&cur[(p >> 8) & 255], 1);
    adj[pos1] = (short)j;
  }
  __syncthreads();

  // accumulate per node (f32 registers, bf16 store)
  for (int n = w; n < 256; n += NW) {
    float2 val = {0.f, 0.f};
    int b0 = off[n], b1 = off[n + 1];
    int k = b0;
    for (; k + 1 < b1; k += 2) {
      float2 a = tof2(zg2[(size_t)adj[k] * 64]);
      float2 b = tof2(zg2[(size_t)adj[k + 1] * 64]);
      val.x += a.x + b.x;
      val.y += a.y + b.y;
    }
    if (k < b1) {
      float2 a = tof2(zg2[(size_t)adj[k] * 64]);
      val.x += a.x; val.y += a.y;
    }
    S2[n * 64 + lane] = tob2(val.x, val.y);
  }
  __syncthreads();

  // gather + eout(bf16) + fused score dot
  const float bbx = bias[2 * lane], bby = bias[2 * lane + 1];
  const float wvx = wsc[2 * lane],  wvy = wsc[2 * lane + 1];
  for (int j = w; j < EG; j += NW) {
    int p = pke[j];
    int s = p & 255, d = (p >> 8) & 255;
    float a_s = as_[j], a_d = ad_[j], a_z = az_[j];
    float2 Sv = tof2(S2[s * 64 + lane]);
    float2 Dv = tof2(S2[d * 64 + lane]);
    float2 zv = tof2(zg2[(size_t)j * 64]);
    float ox = fmaxf(a_s * Sv.x + a_d * Dv.x + a_z * zv.x + bbx, 0.f);
    float oy = fmaxf(a_s * Sv.y + a_d * Dv.y + a_z * zv.y + bby, 0.f);
    eo2[(size_t)j * 64] = tob2(ox, oy);
    float part = ox * wvx + oy * wvy;
#pragma unroll
    for (int offs = 32; offs > 0; offs >>= 1) part += __shfl_xor(part, offs);
    if (lane == 0) zs[(size_t)g * EG + j] = part;
  }
}

// ---------- per-graph score finalize + register-bitonic top-k + compaction ----------
template <int EG, int KEEP, int ENEW>
__global__ __launch_bounds__(512) void k_sortcompact(const float* __restrict__ zs,
                                                     const int* __restrict__ ei_old, int E_old,
                                                     const float* __restrict__ bsc,
                                                     const __bf16* __restrict__ e_old,
                                                     int* __restrict__ ei_new,
                                                     __bf16* __restrict__ e_new,
                                                     float* __restrict__ ew) {
  __shared__ float ls[512];
  __shared__ int   li[512];
  __shared__ int   pke[512];
  __shared__ float Ssh[256], bcs[256];
  __shared__ int   sidx[512];
  const int g = blockIdx.x, t = threadIdx.x;
  if (t < 256) { Ssh[t] = 0.f; bcs[t] = 0.f; }
  __syncthreads();
  float zv = 0.f;
  if (t < EG) {
    int s = ei_old[g * EG + t] & 255, d = ei_old[E_old + g * EG + t] & 255;
    pke[t] = s | (d << 8);
    atomicAdd(&bcs[s], 1.f);
    atomicAdd(&bcs[d], 1.f);
    zv = zs[(size_t)g * EG + t];
  }
  __syncthreads();
  if (t < EG) {
    atomicAdd(&Ssh[pke[t] & 255], zv);
    atomicAdd(&Ssh[(pke[t] >> 8) & 255], zv);
  }
  __syncthreads();
  float s; int idx;
  if (t < EG) {
    int p = pke[t];
    int sn = p & 255, dn = (p >> 8) & 255;
    float bs = bcs[sn], bd = bcs[dn];
    float bis  = (bs != 1.f) ? 1.f / bs : 0.f;
    float bid_ = (bd != 1.f) ? 1.f / bd : 0.f;
    float dnm = 1.f + (bs != 1.f ? 1.f : 0.f) + (bd != 1.f ? 1.f : 0.f);
    s = tanhf((Ssh[sn] * bis + Ssh[dn] * bid_ + zv) / dnm + bsc[0]);
    idx = t;
  } else { s = -INFINITY; idx = 0x7FFFFFFF; }

  // bitonic sort, descending by (score, then idx asc). stride<64 via shuffles.
#pragma unroll
  for (int k = 2; k <= 512; k <<= 1) {
#pragma unroll
    for (int j = k >> 1; j > 0; j >>= 1) {
      float ps; int pi;
      if (j < 64) {
        ps = __shfl_xor(s, j);
        pi = __shfl_xor(idx, j);
      } else {
        ls[t] = s; li[t] = idx;
        __syncthreads();
        ps = ls[t ^ j]; pi = li[t ^ j];
        __syncthreads();
      }
      bool ownBetter = (s > ps) || (s == ps && idx < pi);
      bool lower = ((t & j) == 0);
      bool desc = ((t & k) == 0);
      bool keep = desc ? (lower ? ownBetter : !ownBetter)
                       : (lower ? !ownBetter : ownBetter);
      if (!keep) { s = ps; idx = pi; }
    }
  }

  sidx[t] = idx;
  if (t < KEEP) {
    int oldp = g * EG + idx;
    int newp = g * KEEP + t;
    ei_new[newp]        = ei_old[oldp];
    ei_new[ENEW + newp] = ei_old[E_old + oldp];
    ew[newp] = fminf(fmaxf(s, 0.f), 1.f);
  }
  __syncthreads();
  // compact e rows: 128 bf16 = 256 B = 16 x float4
  const float4* src = (const float4*)e_old;
  float4* dst = (float4*)e_new;
  for (int q = t; q < KEEP * 16; q += 512) {
    int j2 = q >> 4, c = q & 15;
    dst[((size_t)g * KEEP + j2) * 16 + c] = src[((size_t)g * EG + sidx[j2]) * 16 + c];
  }
}

// ---------- final MLP ----------
__global__ __launch_bounds__(128) void k_mlp(const float* __restrict__ xs,
                                             const float* __restrict__ Wc1, const float* __restrict__ bc1,
                                             const float* __restrict__ Wc2, const float* __restrict__ bc2,
                                             const float* __restrict__ Wc3, const float* __restrict__ bc3,
                                             float* __restrict__ out) {
  __shared__ float row[384];
  __shared__ float h1[128];
  __shared__ float h2[64];
  int g = blockIdx.x, t = threadIdx.x;
  for (int i = t; i < 384; i += 128) row[i] = xs[g * 384 + i];
  __syncthreads();
  float a = bc1[t];
  for (int k = 0; k < 384; ++k) a += row[k] * Wc1[k * 128 + t];
  h1[t] = fmaxf(a, 0.f);
  __syncthreads();
  if (t < 64) {
    float b = bc2[t];
    for (int k = 0; k < 128; ++k) b += h1[k] * Wc2[k * 64 + t];
    h2[t] = fmaxf(b, 0.f);
  }
  __syncthreads();
  float o = bc3[t];
  for (int k = 0; k < 64; ++k) o += h2[k] * Wc3[k * 128 + t];
  out[g * 128 + t] = o;
}

extern "C" void kernel_launch(void* const* d_in, const int* in_sizes, int n_in,
                              void* d_out, int out_size, void* d_ws, size_t ws_size,
                              hipStream_t stream) {
  (void)in_sizes; (void)n_in; (void)out_size; (void)ws_size;
  const int*   x_idx  = (const int*)d_in[0];
  const int*   b_idx  = (const int*)d_in[1];
  const int*   ei0    = (const int*)d_in[2];
  const float* atom_t = (const float*)d_in[4];
  const float* bond_t = (const float*)d_in[5];
  const float* W_gcn  = (const float*)d_in[6];
  const float* b_gcn  = (const float*)d_in[7];
  const float* root   = (const float*)d_in[8];
  const float* W_hyp  = (const float*)d_in[9];
  const float* b_hyp  = (const float*)d_in[10];
  const float* W_sc   = (const float*)d_in[11];
  const float* b_sc   = (const float*)d_in[12];
  const float* Wc1    = (const float*)d_in[13];
  const float* bc1_   = (const float*)d_in[14];
  const float* Wc2    = (const float*)d_in[15];
  const float* bc2_   = (const float*)d_in[16];
  const float* Wc3    = (const float*)d_in[17];
  const float* bc3_   = (const float*)d_in[18];
  float* out = (float*)d_out;

  // workspace layout: bf16 activations first, then f32 scalars
  __bf16* x  = (__bf16*)d_ws;
  __bf16* eA = x  + (size_t)NTOT * D;
  __bf16* eB = eA + (size_t)E0 * D;
  float* zs  = (float*)(eB + (size_t)E0 * D);
  float* ew  = zs + E0;
  float* xs  = ew + E0;
  int*   eiB  = (int*)(xs + BG * 384);
  int*   eiA2 = eiB + 2 * E0;

  hipMemsetAsync(xs, 0, BG * 384 * 4, stream);
  k_embed_x<<<NTOT * 32 / 256, 256, 0, stream>>>(x_idx, atom_t, x);
  k_embed_e<<<E0 * 32 / 256, 256, 0, stream>>>(b_idx, bond_t, eA);

  // ---- layer 0 ----
  k_gcn_fused<EG0, false><<<BG, 1024, 0, stream>>>(ei0, E0, eA, W_gcn, b_gcn, nullptr, root, x, xs);
  k_gemm_bf16<<<E0 / 128, 256, 0, stream>>>(eA, W_hyp, nullptr, eB);
  k_hyper_fused<EG0><<<BG, 1024, 0, stream>>>(ei0, E0, eB, b_hyp, W_sc, eA, zs);
  k_sortcompact<EG0, KP0, E1><<<BG, 512, 0, stream>>>(zs, ei0, E0, b_sc, eA, eiB, eB, ew);

  // ---- layer 1 ----
  k_gcn_fused<KP0, true><<<BG, 1024, 0, stream>>>(eiB, E1, eB, W_gcn + D * D, b_gcn + D, ew, root + D, x, xs);
  k_gemm_bf16<<<E1 / 128, 256, 0, stream>>>(eB, W_hyp + D * D, nullptr, eA);
  k_hyper_fused<KP0><<<BG, 1024, 0, stream>>>(eiB, E1, eA, b_hyp + D, W_sc + D, eB, zs);
  k_sortcompact<KP0, KP1, E2><<<BG, 512, 0, stream>>>(zs, eiB, E1, b_sc + 1, eB, eiA2, eA, ew);

  // ---- layer 2 ----
  k_gcn_fused<KP1, true><<<BG, 1024, 0, stream>>>(eiA2, E2, eA, W_gcn + 2 * D * D, b_gcn + 2 * D, ew, root + 2 * D, x, xs);

  k_mlp<<<BG, 128, 0, stream>>>(xs, Wc1, bc1_, Wc2, bc2_, Wc3, bc3_, out);
}

// Round 17
// 251.866 us; speedup vs baseline: 1.0669x; 1.0669x over previous
//
#include <hip/hip_runtime.h>
#include <hip/hip_bf16.h>
#include <math.h>

constexpr int NTOT = 65536;
constexpr int D    = 128;
constexpr int BG   = 256;
constexpr int E0 = 131072, E1 = 104960, E2 = 83968;
constexpr int EG0 = 512;
constexpr int KP0 = 410, KP1 = 328;

typedef __bf16 bf16x8 __attribute__((ext_vector_type(8)));
typedef __bf16 bf16x4 __attribute__((ext_vector_type(4)));
typedef __bf16 bf16x2 __attribute__((ext_vector_type(2)));
typedef float  f32x4  __attribute__((ext_vector_type(4)));

__device__ __forceinline__ float2 tof2(bf16x2 v) {
  return make_float2((float)v[0], (float)v[1]);
}
__device__ __forceinline__ bf16x2 tob2(float ax, float ay) {
  bf16x2 r; r[0] = (__bf16)ax; r[1] = (__bf16)ay; return r;
}

// ---------- embeddings (f32 tables -> bf16 activations) ----------
__global__ __launch_bounds__(256) void k_embed_x(const int* __restrict__ xi,
                                                 const float* __restrict__ tab,
                                                 __bf16* __restrict__ x) {
  int t = blockIdx.x * 256 + threadIdx.x;      // NTOT*32 threads
  int v = t >> 5, q = (t & 31) << 2;
  float4 s = {0.f, 0.f, 0.f, 0.f};
#pragma unroll
  for (int j = 0; j < 9; ++j) {
    int r = xi[v * 9 + j];
    float4 a = *(const float4*)&tab[r * D + q];
    s.x += a.x; s.y += a.y; s.z += a.z; s.w += a.w;
  }
  bf16x4 o; o[0] = (__bf16)s.x; o[1] = (__bf16)s.y; o[2] = (__bf16)s.z; o[3] = (__bf16)s.w;
  *(bf16x4*)&x[(size_t)v * D + q] = o;
}

__global__ __launch_bounds__(256) void k_embed_e(const int* __restrict__ bi,
                                                 const float* __restrict__ tab,
                                                 __bf16* __restrict__ e) {
  int t = blockIdx.x * 256 + threadIdx.x;      // E0*32 threads
  int i = t >> 5, q = (t & 31) << 2;
  float4 s = {0.f, 0.f, 0.f, 0.f};
#pragma unroll
  for (int j = 0; j < 3; ++j) {
    int r = bi[i * 3 + j];
    float4 a = *(const float4*)&tab[r * D + q];
    s.x += a.x; s.y += a.y; s.z += a.z; s.w += a.w;
  }
  bf16x4 o; o[0] = (__bf16)s.x; o[1] = (__bf16)s.y; o[2] = (__bf16)s.z; o[3] = (__bf16)s.w;
  *(bf16x4*)&e[(size_t)i * D + q] = o;
}

// ---------- bf16 MFMA GEMM (for z = e @ W_hyp): C = A @ W, A/C bf16 ----------
__global__ __launch_bounds__(256) void k_gemm_bf16(const __bf16* __restrict__ A,
                                                   const float* __restrict__ W,
                                                   const float* __restrict__ bias,
                                                   __bf16* __restrict__ C) {
  __shared__ bf16x8 Wl[4][8][64];              // [ks][nt][lane] fragments, 32 KB
  const int t = threadIdx.x, w = t >> 6, lane = t & 63;
  const int m0 = blockIdx.x * 128;

  bf16x8* Wf = (bf16x8*)Wl;
  for (int q = t; q < 2048; q += 256) {
    int ks = q >> 9, nt = (q >> 6) & 7, l = q & 63;
    int kk = ks * 32 + ((l >> 4) << 3);
    int nn = nt * 16 + (l & 15);
    const float* wp = W + (size_t)kk * 128 + nn;
    bf16x8 v;
#pragma unroll
    for (int b = 0; b < 8; ++b) v[b] = (__bf16)wp[(size_t)b * 128];
    Wf[q] = v;
  }

  const int r0 = m0 + w * 32 + (lane & 15);
  const __bf16* Ap0 = A + (size_t)r0 * 128 + ((lane >> 4) << 3);
  const __bf16* Ap1 = Ap0 + 16 * 128;
  bf16x8 a0[4], a1[4];
#pragma unroll
  for (int ks = 0; ks < 4; ++ks) {
    a0[ks] = *(const bf16x8*)(Ap0 + ks * 32);
    a1[ks] = *(const bf16x8*)(Ap1 + ks * 32);
  }
  __syncthreads();

  f32x4 acc0[8] = {}; f32x4 acc1[8] = {};
#pragma unroll
  for (int ks = 0; ks < 4; ++ks) {
#pragma unroll
    for (int nt = 0; nt < 8; ++nt) {
      bf16x8 b = Wl[ks][nt][lane];
      acc0[nt] = __builtin_amdgcn_mfma_f32_16x16x32_bf16(a0[ks], b, acc0[nt], 0, 0, 0);
      acc1[nt] = __builtin_amdgcn_mfma_f32_16x16x32_bf16(a1[ks], b, acc1[nt], 0, 0, 0);
    }
  }

  const int orow = m0 + w * 32 + ((lane >> 4) << 2);
  const int ocol = lane & 15;
#pragma unroll
  for (int nt = 0; nt < 8; ++nt) {
    float bb = bias ? bias[nt * 16 + ocol] : 0.f;
    __bf16* cp = C + (size_t)orow * 128 + nt * 16 + ocol;
#pragma unroll
    for (int r = 0; r < 4; ++r) {
      cp[(size_t)r * 128]        = (__bf16)(acc0[nt][r] + bb);
      cp[(size_t)(16 + r) * 128] = (__bf16)(acc1[nt][r] + bb);
    }
  }
}

// ---------- MEGA GCN layer: fused h = x@Wg + b (MFMA into LDS) + CSR message
//            passing + finalize + in-place x update + readout.
//            1 block/graph, 1024 thr (16 waves x 16 rows). ----------
template <int EG, bool HAS_EW>
__global__ __launch_bounds__(1024, 4) void k_gcn_fused(const int* __restrict__ ei, int E,
                                                       const __bf16* __restrict__ e,
                                                       const float* __restrict__ Wg,
                                                       const float* __restrict__ bg,
                                                       const float* __restrict__ ew,
                                                       const float* __restrict__ root,
                                                       __bf16* __restrict__ x,
                                                       float* __restrict__ xs) {
  constexpr int NW = 16;
  __shared__ bf16x8 Wl[4][8][64];             // 32 KB W fragments
  __shared__ __bf16 hl[256 * 128];            // 64 KB h tile
  __shared__ int   pke[EG];
  __shared__ float coef[EG];
  __shared__ int   cnts[256];
  __shared__ int   cntd[256];
  __shared__ int   off[257];
  __shared__ int   cur[256];
  __shared__ int   wsum[4];
  __shared__ short adj[EG];
  __shared__ float redm[16 * 128], reds[16 * 128];   // 16 KB
  const int g = blockIdx.x;
  const int t = threadIdx.x, w = t >> 6, lane = t & 63;
  const bf16x2* eg2 = (const bf16x2*)e + (size_t)g * EG * 64 + lane;
  bf16x2* xg2 = (bf16x2*)x + (size_t)g * 256 * 64 + lane;

  if (t < 256) { cnts[t] = 0; cntd[t] = 0; }
  __syncthreads();

  // Phase 1: CSR counts + packed indices, and W fragment staging (independent)
  for (int j = t; j < EG; j += 1024) {
    int s = ei[g * EG + j] & 255, d = ei[E + g * EG + j] & 255;
    pke[j] = s | (d << 8);
    atomicAdd(&cnts[s], 1);
    atomicAdd(&cntd[d], 1);
  }
  {
    bf16x8* Wf = (bf16x8*)Wl;
    for (int q = t; q < 2048; q += 1024) {
      int ks = q >> 9, nt = (q >> 6) & 7, l = q & 63;
      int kk = ks * 32 + ((l >> 4) << 3);
      int nn = nt * 16 + (l & 15);
      const float* wp = Wg + (size_t)kk * 128 + nn;
      bf16x8 v;
#pragma unroll
      for (int b = 0; b < 8; ++b) v[b] = (__bf16)wp[(size_t)b * 128];
      Wf[q] = v;
    }
  }
  __syncthreads();

  // Phase 2a: MFMA h = x@Wg + bg for this graph's 256 rows -> LDS hl
  {
    const int r0 = w * 16 + (lane & 15);
    const __bf16* Ap = x + ((size_t)(g * 256 + r0)) * 128 + ((lane >> 4) << 3);
    bf16x8 af[4];
#pragma unroll
    for (int ks = 0; ks < 4; ++ks) af[ks] = *(const bf16x8*)(Ap + ks * 32);
    f32x4 acc[8] = {};
#pragma unroll
    for (int ks = 0; ks < 4; ++ks) {
#pragma unroll
      for (int nt = 0; nt < 8; ++nt) {
        acc[nt] = __builtin_amdgcn_mfma_f32_16x16x32_bf16(af[ks], Wl[ks][nt][lane], acc[nt], 0, 0, 0);
      }
    }
    const int lrow = w * 16 + ((lane >> 4) << 2);
    const int ocol = lane & 15;
#pragma unroll
    for (int nt = 0; nt < 8; ++nt) {
      float bb = bg[nt * 16 + ocol];
#pragma unroll
      for (int r = 0; r < 4; ++r)
        hl[(lrow + r) * 128 + nt * 16 + ocol] = (__bf16)(acc[nt][r] + bb);
    }
  }

  // Phase 2b: per-edge coefficient
  for (int j = t; j < EG; j += 1024) {
    int p = pke[j];
    int s = p & 255, d = (p >> 8) & 255;
    float c = rsqrtf(((float)cnts[s] + 1.f) * ((float)cnts[d] + 1.f));
    if (HAS_EW) c *= ew[g * EG + j];
    coef[j] = c;
  }

  // Phase 2c: wave-shuffle exclusive scan of cntd (2 barriers)
  {
    int v = 0;
    if (t < 256) {
      v = cntd[t];
#pragma unroll
      for (int d2 = 1; d2 < 64; d2 <<= 1) {
        int u = __shfl_up(v, d2);
        if (lane >= d2) v += u;
      }
      if (lane == 63) wsum[w] = v;
    }
    __syncthreads();
    if (t < 256) {
      int add = 0;
      if (w > 0) add += wsum[0];
      if (w > 1) add += wsum[1];
      if (w > 2) add += wsum[2];
      off[t + 1] = v + add;
      if (t == 0) off[0] = 0;
      cur[t] = v + add - cntd[t];
    }
    __syncthreads();
  }

  for (int j = t; j < EG; j += 1024) {
    int d = (pke[j] >> 8) & 255;
    int pos = atomicAdd(&cur[d], 1);
    adj[pos] = (short)j;
  }
  __syncthreads();

  // Phase 3: per-node accumulate (e global, h LDS) + finalize + x + readout
  const float rvx = root[2 * lane], rvy = root[2 * lane + 1];
  float2 mx = {-1e30f, -1e30f}, sm = {0.f, 0.f};
  for (int n = w; n < 256; n += NW) {
    float2 val = {0.f, 0.f};
    int b0 = off[n], b1 = off[n + 1];
    int k = b0;
    for (; k + 1 < b1; k += 2) {
      int j0 = adj[k], j1 = adj[k + 1];
      int s0 = pke[j0] & 255, s1 = pke[j1] & 255;
      float2 e0 = tof2(eg2[(size_t)j0 * 64]), e1 = tof2(eg2[(size_t)j1 * 64]);
      float2 h0 = tof2(*(const bf16x2*)&hl[s0 * 128 + 2 * lane]);
      float2 h1 = tof2(*(const bf16x2*)&hl[s1 * 128 + 2 * lane]);
      float c0 = coef[j0], c1 = coef[j1];
      val.x += c0 * fmaxf(h0.x + e0.x, 0.f) + c1 * fmaxf(h1.x + e1.x, 0.f);
      val.y += c0 * fmaxf(h0.y + e0.y, 0.f) + c1 * fmaxf(h1.y + e1.y, 0.f);
    }
    if (k < b1) {
      int j0 = adj[k];
      int s0 = pke[j0] & 255;
      float2 e0 = tof2(eg2[(size_t)j0 * 64]);
      float2 h0 = tof2(*(const bf16x2*)&hl[s0 * 128 + 2 * lane]);
      float c0 = coef[j0];
      val.x += c0 * fmaxf(h0.x + e0.x, 0.f);
      val.y += c0 * fmaxf(h0.y + e0.y, 0.f);
    }
    float inv = 1.f / ((float)cnts[n] + 1.f);
    float2 hv = tof2(*(const bf16x2*)&hl[n * 128 + 2 * lane]);
    float xvx = fmaxf(val.x + fmaxf(hv.x + rvx, 0.f) * inv, 0.f);
    float xvy = fmaxf(val.y + fmaxf(hv.y + rvy, 0.f) * inv, 0.f);
    xg2[(size_t)n * 64] = tob2(xvx, xvy);
    mx.x = fmaxf(mx.x, xvx); mx.y = fmaxf(mx.y, xvy);
    sm.x += xvx;             sm.y += xvy;
  }
  redm[w * 128 + 2 * lane]     = mx.x;
  redm[w * 128 + 2 * lane + 1] = mx.y;
  reds[w * 128 + 2 * lane]     = sm.x;
  reds[w * 128 + 2 * lane + 1] = sm.y;
  __syncthreads();

  if (t < 128) {
    float M = redm[t], S2 = reds[t];
#pragma unroll
    for (int k = 1; k < 16; ++k) {
      M = fmaxf(M, redm[k * 128 + t]);
      S2 += reds[k * 128 + t];
    }
    xs[g * 384 + t]       += M;
    xs[g * 384 + 128 + t] += S2 * (1.f / 256.f);
    xs[g * 384 + 256 + t] += S2;
  }
}

// ---------- MEGA hyperconv + top-k: CSR + gather + eout + score +
//            register-bitonic sort + compaction, all in one kernel.
//            1 block/graph, 1024 thr. ----------
template <int EG, int KEEP, int ENEW>
__global__ __launch_bounds__(1024, 4) void k_hyper_sort(const int* __restrict__ ei, int E,
                                                        const __bf16* __restrict__ z,
                                                        const float* __restrict__ bias,
                                                        const float* __restrict__ wsc,
                                                        const float* __restrict__ bsc,
                                                        __bf16* __restrict__ eout,
                                                        int* __restrict__ ei_new,
                                                        __bf16* __restrict__ e_new,
                                                        float* __restrict__ ew) {
  constexpr int NW = 16;
  __shared__ __bf16 S[256 * 128];             // 64 KB (bf16)
  __shared__ int   pke[EG];
  __shared__ float as_[EG], ad_[EG], az_[EG];
  __shared__ float zsh[EG];
  __shared__ float Ssh[256];
  __shared__ int   cnt[256];
  __shared__ int   off[257];
  __shared__ int   cur[256];
  __shared__ int   wsum[4];
  __shared__ short adj[2 * EG];
  __shared__ float ls[512];
  __shared__ int   li[512];
  __shared__ int   sidx[512];
  const int g = blockIdx.x;
  const int t = threadIdx.x, w = t >> 6, lane = t & 63;
  const bf16x2* zg2 = (const bf16x2*)z + (size_t)g * EG * 64 + lane;
  bf16x2* eo2 = (bf16x2*)eout + (size_t)g * EG * 64 + lane;
  bf16x2* S2 = (bf16x2*)S;

  if (t < 256) { cnt[t] = 0; Ssh[t] = 0.f; }
  __syncthreads();

  for (int j = t; j < EG; j += 1024) {
    int s = ei[g * EG + j] & 255, d = ei[E + g * EG + j] & 255;
    pke[j] = s | (d << 8);
    atomicAdd(&cnt[s], 1);
    atomicAdd(&cnt[d], 1);
  }
  __syncthreads();

  // per-edge gather constants
  for (int j = t; j < EG; j += 1024) {
    int p = pke[j];
    int s = p & 255, d = (p >> 8) & 255;
    int cs = cnt[s], cd = cnt[d];
    float bis  = (cs != 1) ? 1.f / (float)cs : 0.f;
    float bid_ = (cd != 1) ? 1.f / (float)cd : 0.f;
    float dinv = 1.f / (1.f + (cs != 1 ? 1.f : 0.f) + (cd != 1 ? 1.f : 0.f));
    as_[j] = dinv * bis;
    ad_[j] = dinv * bid_;
    az_[j] = dinv;
  }

  // wave-shuffle exclusive scan of cnt (2 barriers)
  {
    int v = 0;
    if (t < 256) {
      v = cnt[t];
#pragma unroll
      for (int d2 = 1; d2 < 64; d2 <<= 1) {
        int u = __shfl_up(v, d2);
        if (lane >= d2) v += u;
      }
      if (lane == 63) wsum[w] = v;
    }
    __syncthreads();
    if (t < 256) {
      int add = 0;
      if (w > 0) add += wsum[0];
      if (w > 1) add += wsum[1];
      if (w > 2) add += wsum[2];
      off[t + 1] = v + add;
      if (t == 0) off[0] = 0;
      cur[t] = v + add - cnt[t];
    }
    __syncthreads();
  }

  for (int j = t; j < EG; j += 1024) {
    int p = pke[j];
    int pos0 = atomicAdd(&cur[p & 255], 1);
    adj[pos0] = (short)j;
    int pos1 = atomicAdd(&cur[(p >> 8) & 255], 1);
    adj[pos1] = (short)j;
  }
  __syncthreads();

  // accumulate per node (f32 registers, bf16 store)
  for (int n = w; n < 256; n += NW) {
    float2 val = {0.f, 0.f};
    int b0 = off[n], b1 = off[n + 1];
    int k = b0;
    for (; k + 1 < b1; k += 2) {
      float2 a = tof2(zg2[(size_t)adj[k] * 64]);
      float2 b = tof2(zg2[(size_t)adj[k + 1] * 64]);
      val.x += a.x + b.x;
      val.y += a.y + b.y;
    }
    if (k < b1) {
      float2 a = tof2(zg2[(size_t)adj[k] * 64]);
      val.x += a.x; val.y += a.y;
    }
    S2[n * 64 + lane] = tob2(val.x, val.y);
  }
  __syncthreads();

  // gather + eout(bf16) + score dot -> zsh (LDS)
  const float bbx = bias[2 * lane], bby = bias[2 * lane + 1];
  const float wvx = wsc[2 * lane],  wvy = wsc[2 * lane + 1];
  for (int j = w; j < EG; j += NW) {
    int p = pke[j];
    int s = p & 255, d = (p >> 8) & 255;
    float a_s = as_[j], a_d = ad_[j], a_z = az_[j];
    float2 Sv = tof2(S2[s * 64 + lane]);
    float2 Dv = tof2(S2[d * 64 + lane]);
    float2 zv = tof2(zg2[(size_t)j * 64]);
    float ox = fmaxf(a_s * Sv.x + a_d * Dv.x + a_z * zv.x + bbx, 0.f);
    float oy = fmaxf(a_s * Sv.y + a_d * Dv.y + a_z * zv.y + bby, 0.f);
    eo2[(size_t)j * 64] = tob2(ox, oy);
    float part = ox * wvx + oy * wvy;
#pragma unroll
    for (int offs = 32; offs > 0; offs >>= 1) part += __shfl_xor(part, offs);
    if (lane == 0) zsh[j] = part;
  }
  __syncthreads();

  // scalar hyperconv on scores: Ssh[n] = sum of zsh over incident edges
  if (t < EG) {
    float v = zsh[t];
    atomicAdd(&Ssh[pke[t] & 255], v);
    atomicAdd(&Ssh[(pke[t] >> 8) & 255], v);
  }
  __syncthreads();

  // score finalize + bitonic sort (waves 0-7 hold one element each)
  float sc = -INFINITY; int idx = 0x7FFFFFFF;
  if (t < EG) {
    int p = pke[t];
    int sn = p & 255, dn = (p >> 8) & 255;
    sc = tanhf(as_[t] * Ssh[sn] + ad_[t] * Ssh[dn] + az_[t] * zsh[t] + bsc[0]);
    idx = t;
  }
#pragma unroll
  for (int k = 2; k <= 512; k <<= 1) {
#pragma unroll
    for (int j = k >> 1; j > 0; j >>= 1) {
      if (j < 64) {
        if (t < 512) {
          float ps = __shfl_xor(sc, j);
          int   pi = __shfl_xor(idx, j);
          bool ownBetter = (sc > ps) || (sc == ps && idx < pi);
          bool lower = ((t & j) == 0);
          bool desc = ((t & k) == 0);
          bool keep = desc ? (lower ? ownBetter : !ownBetter)
                           : (lower ? !ownBetter : ownBetter);
          if (!keep) { sc = ps; idx = pi; }
        }
      } else {
        if (t < 512) { ls[t] = sc; li[t] = idx; }
        __syncthreads();
        if (t < 512) {
          float ps = ls[t ^ j];
          int   pi = li[t ^ j];
          bool ownBetter = (sc > ps) || (sc == ps && idx < pi);
          bool lower = ((t & j) == 0);
          bool desc = ((t & k) == 0);
          bool keep = desc ? (lower ? ownBetter : !ownBetter)
                           : (lower ? !ownBetter : ownBetter);
          if (!keep) { sc = ps; idx = pi; }
        }
        __syncthreads();
      }
    }
  }

  if (t < 512) sidx[t] = idx;
  if (t < KEEP) {
    int oldp = g * EG + idx;
    int newp = g * KEEP + t;
    ei_new[newp]        = ei[oldp];
    ei_new[ENEW + newp] = ei[E + oldp];
    ew[newp] = fminf(fmaxf(sc, 0.f), 1.f);
  }
  __syncthreads();

  // compaction: copy eout rows (written above; barrier-ordered, same CU/L2)
  const float4* src = (const float4*)eout;
  float4* dst = (float4*)e_new;
  for (int q = t; q < KEEP * 16; q += 1024) {
    int j2 = q >> 4, c = q & 15;
    dst[((size_t)g * KEEP + j2) * 16 + c] = src[((size_t)g * EG + sidx[j2]) * 16 + c];
  }
}

// ---------- final MLP ----------
__global__ __launch_bounds__(128) void k_mlp(const float* __restrict__ xs,
                                             const float* __restrict__ Wc1, const float* __restrict__ bc1,
                                             const float* __restrict__ Wc2, const float* __restrict__ bc2,
                                             const float* __restrict__ Wc3, const float* __restrict__ bc3,
                                             float* __restrict__ out) {
  __shared__ float row[384];
  __shared__ float h1[128];
  __shared__ float h2[64];
  int g = blockIdx.x, t = threadIdx.x;
  for (int i = t; i < 384; i += 128) row[i] = xs[g * 384 + i];
  __syncthreads();
  float a = bc1[t];
  for (int k = 0; k < 384; ++k) a += row[k] * Wc1[k * 128 + t];
  h1[t] = fmaxf(a, 0.f);
  __syncthreads();
  if (t < 64) {
    float b = bc2[t];
    for (int k = 0; k < 128; ++k) b += h1[k] * Wc2[k * 64 + t];
    h2[t] = fmaxf(b, 0.f);
  }
  __syncthreads();
  float o = bc3[t];
  for (int k = 0; k < 64; ++k) o += h2[k] * Wc3[k * 128 + t];
  out[g * 128 + t] = o;
}

extern "C" void kernel_launch(void* const* d_in, const int* in_sizes, int n_in,
                              void* d_out, int out_size, void* d_ws, size_t ws_size,
                              hipStream_t stream) {
  (void)in_sizes; (void)n_in; (void)out_size; (void)ws_size;
  const int*   x_idx  = (const int*)d_in[0];
  const int*   b_idx  = (const int*)d_in[1];
  const int*   ei0    = (const int*)d_in[2];
  const float* atom_t = (const float*)d_in[4];
  const float* bond_t = (const float*)d_in[5];
  const float* W_gcn  = (const float*)d_in[6];
  const float* b_gcn  = (const float*)d_in[7];
  const float* root   = (const float*)d_in[8];
  const float* W_hyp  = (const float*)d_in[9];
  const float* b_hyp  = (const float*)d_in[10];
  const float* W_sc   = (const float*)d_in[11];
  const float* b_sc   = (const float*)d_in[12];
  const float* Wc1    = (const float*)d_in[13];
  const float* bc1_   = (const float*)d_in[14];
  const float* Wc2    = (const float*)d_in[15];
  const float* bc2_   = (const float*)d_in[16];
  const float* Wc3    = (const float*)d_in[17];
  const float* bc3_   = (const float*)d_in[18];
  float* out = (float*)d_out;

  // workspace layout: bf16 activations first, then f32 scalars
  __bf16* x  = (__bf16*)d_ws;
  __bf16* eA = x  + (size_t)NTOT * D;
  __bf16* eB = eA + (size_t)E0 * D;
  float* ew  = (float*)(eB + (size_t)E0 * D);
  float* xs  = ew + E0;
  int*   eiB  = (int*)(xs + BG * 384);
  int*   eiA2 = eiB + 2 * E0;

  hipMemsetAsync(xs, 0, BG * 384 * 4, stream);
  k_embed_x<<<NTOT * 32 / 256, 256, 0, stream>>>(x_idx, atom_t, x);
  k_embed_e<<<E0 * 32 / 256, 256, 0, stream>>>(b_idx, bond_t, eA);

  // ---- layer 0 ----
  k_gcn_fused<EG0, false><<<BG, 1024, 0, stream>>>(ei0, E0, eA, W_gcn, b_gcn, nullptr, root, x, xs);
  k_gemm_bf16<<<E0 / 128, 256, 0, stream>>>(eA, W_hyp, nullptr, eB);
  k_hyper_sort<EG0, KP0, E1><<<BG, 1024, 0, stream>>>(ei0, E0, eB, b_hyp, W_sc, b_sc, eA, eiB, eB, ew);

  // ---- layer 1 ----
  k_gcn_fused<KP0, true><<<BG, 1024, 0, stream>>>(eiB, E1, eB, W_gcn + D * D, b_gcn + D, ew, root + D, x, xs);
  k_gemm_bf16<<<E1 / 128, 256, 0, stream>>>(eB, W_hyp + D * D, nullptr, eA);
  k_hyper_sort<KP0, KP1, E2><<<BG, 1024, 0, stream>>>(eiB, E1, eA, b_hyp + D, W_sc + D, b_sc + 1, eB, eiA2, eA, ew);

  // ---- layer 2 ----
  k_gcn_fused<KP1, true><<<BG, 1024, 0, stream>>>(eiA2, E2, eA, W_gcn + 2 * D * D, b_gcn + 2 * D, ew, root + 2 * D, x, xs);

  k_mlp<<<BG, 128, 0, stream>>>(xs, Wc1, bc1_, Wc2, bc2_, Wc3, bc3_, out);
}

// Round 18
// 225.072 us; speedup vs baseline: 1.1939x; 1.1190x over previous
//
#include <hip/hip_runtime.h>
#include <hip/hip_bf16.h>
#include <math.h>

constexpr int NTOT = 65536;
constexpr int D    = 128;
constexpr int BG   = 256;
constexpr int E0 = 131072, E1 = 104960, E2 = 83968;
constexpr int EG0 = 512;
constexpr int KP0 = 410, KP1 = 328;

typedef __bf16 bf16x8 __attribute__((ext_vector_type(8)));
typedef __bf16 bf16x4 __attribute__((ext_vector_type(4)));
typedef __bf16 bf16x2 __attribute__((ext_vector_type(2)));
typedef float  f32x4  __attribute__((ext_vector_type(4)));

__device__ __forceinline__ float2 tof2(bf16x2 v) {
  return make_float2((float)v[0], (float)v[1]);
}
__device__ __forceinline__ bf16x2 tob2(float ax, float ay) {
  bf16x2 r; r[0] = (__bf16)ax; r[1] = (__bf16)ay; return r;
}

// ---------- embeddings (f32 tables -> bf16 activations) ----------
__global__ __launch_bounds__(256) void k_embed_x(const int* __restrict__ xi,
                                                 const float* __restrict__ tab,
                                                 __bf16* __restrict__ x) {
  int t = blockIdx.x * 256 + threadIdx.x;      // NTOT*32 threads
  int v = t >> 5, q = (t & 31) << 2;
  float4 s = {0.f, 0.f, 0.f, 0.f};
#pragma unroll
  for (int j = 0; j < 9; ++j) {
    int r = xi[v * 9 + j];
    float4 a = *(const float4*)&tab[r * D + q];
    s.x += a.x; s.y += a.y; s.z += a.z; s.w += a.w;
  }
  bf16x4 o; o[0] = (__bf16)s.x; o[1] = (__bf16)s.y; o[2] = (__bf16)s.z; o[3] = (__bf16)s.w;
  *(bf16x4*)&x[(size_t)v * D + q] = o;
}

__global__ __launch_bounds__(256) void k_embed_e(const int* __restrict__ bi,
                                                 const float* __restrict__ tab,
                                                 __bf16* __restrict__ e) {
  int t = blockIdx.x * 256 + threadIdx.x;      // E0*32 threads
  int i = t >> 5, q = (t & 31) << 2;
  float4 s = {0.f, 0.f, 0.f, 0.f};
#pragma unroll
  for (int j = 0; j < 3; ++j) {
    int r = bi[i * 3 + j];
    float4 a = *(const float4*)&tab[r * D + q];
    s.x += a.x; s.y += a.y; s.z += a.z; s.w += a.w;
  }
  bf16x4 o; o[0] = (__bf16)s.x; o[1] = (__bf16)s.y; o[2] = (__bf16)s.z; o[3] = (__bf16)s.w;
  *(bf16x4*)&e[(size_t)i * D + q] = o;
}

// ---------- MEGA GCN layer: fused h = x@Wg + b (MFMA into LDS) + CSR message
//            passing + finalize + in-place x update + readout.
//            1 block/graph, 1024 thr (16 waves x 16 rows). ----------
template <int EG, bool HAS_EW>
__global__ __launch_bounds__(1024, 4) void k_gcn_fused(const int* __restrict__ ei, int E,
                                                       const __bf16* __restrict__ e,
                                                       const float* __restrict__ Wg,
                                                       const float* __restrict__ bg,
                                                       const float* __restrict__ ew,
                                                       const float* __restrict__ root,
                                                       __bf16* __restrict__ x,
                                                       float* __restrict__ xs) {
  constexpr int NW = 16;
  __shared__ bf16x8 Wl[4][8][64];             // 32 KB W fragments
  __shared__ __bf16 hl[256 * 128];            // 64 KB h tile
  __shared__ int   pke[EG];
  __shared__ float coef[EG];
  __shared__ int   cnts[256];
  __shared__ int   cntd[256];
  __shared__ int   off[257];
  __shared__ int   cur[256];
  __shared__ int   wsum[4];
  __shared__ short adj[EG];
  __shared__ float redm[16 * 128], reds[16 * 128];   // 16 KB
  const int g = blockIdx.x;
  const int t = threadIdx.x, w = t >> 6, lane = t & 63;
  const bf16x2* eg2 = (const bf16x2*)e + (size_t)g * EG * 64 + lane;
  bf16x2* xg2 = (bf16x2*)x + (size_t)g * 256 * 64 + lane;

  if (t < 256) { cnts[t] = 0; cntd[t] = 0; }
  __syncthreads();

  // Phase 1: CSR counts + packed indices, and W fragment staging (independent)
  for (int j = t; j < EG; j += 1024) {
    int s = ei[g * EG + j] & 255, d = ei[E + g * EG + j] & 255;
    pke[j] = s | (d << 8);
    atomicAdd(&cnts[s], 1);
    atomicAdd(&cntd[d], 1);
  }
  {
    bf16x8* Wf = (bf16x8*)Wl;
    for (int q = t; q < 2048; q += 1024) {
      int ks = q >> 9, nt = (q >> 6) & 7, l = q & 63;
      int kk = ks * 32 + ((l >> 4) << 3);
      int nn = nt * 16 + (l & 15);
      const float* wp = Wg + (size_t)kk * 128 + nn;
      bf16x8 v;
#pragma unroll
      for (int b = 0; b < 8; ++b) v[b] = (__bf16)wp[(size_t)b * 128];
      Wf[q] = v;
    }
  }
  __syncthreads();

  // Phase 2a: MFMA h = x@Wg + bg for this graph's 256 rows -> LDS hl
  {
    const int r0 = w * 16 + (lane & 15);
    const __bf16* Ap = x + ((size_t)(g * 256 + r0)) * 128 + ((lane >> 4) << 3);
    bf16x8 af[4];
#pragma unroll
    for (int ks = 0; ks < 4; ++ks) af[ks] = *(const bf16x8*)(Ap + ks * 32);
    f32x4 acc[8] = {};
#pragma unroll
    for (int ks = 0; ks < 4; ++ks) {
#pragma unroll
      for (int nt = 0; nt < 8; ++nt) {
        acc[nt] = __builtin_amdgcn_mfma_f32_16x16x32_bf16(af[ks], Wl[ks][nt][lane], acc[nt], 0, 0, 0);
      }
    }
    const int lrow = w * 16 + ((lane >> 4) << 2);
    const int ocol = lane & 15;
#pragma unroll
    for (int nt = 0; nt < 8; ++nt) {
      float bb = bg[nt * 16 + ocol];
#pragma unroll
      for (int r = 0; r < 4; ++r)
        hl[(lrow + r) * 128 + nt * 16 + ocol] = (__bf16)(acc[nt][r] + bb);
    }
  }

  // Phase 2b: per-edge coefficient
  for (int j = t; j < EG; j += 1024) {
    int p = pke[j];
    int s = p & 255, d = (p >> 8) & 255;
    float c = rsqrtf(((float)cnts[s] + 1.f) * ((float)cnts[d] + 1.f));
    if (HAS_EW) c *= ew[g * EG + j];
    coef[j] = c;
  }

  // Phase 2c: wave-shuffle exclusive scan of cntd (2 barriers)
  {
    int v = 0;
    if (t < 256) {
      v = cntd[t];
#pragma unroll
      for (int d2 = 1; d2 < 64; d2 <<= 1) {
        int u = __shfl_up(v, d2);
        if (lane >= d2) v += u;
      }
      if (lane == 63) wsum[w] = v;
    }
    __syncthreads();
    if (t < 256) {
      int add = 0;
      if (w > 0) add += wsum[0];
      if (w > 1) add += wsum[1];
      if (w > 2) add += wsum[2];
      off[t + 1] = v + add;
      if (t == 0) off[0] = 0;
      cur[t] = v + add - cntd[t];
    }
    __syncthreads();
  }

  for (int j = t; j < EG; j += 1024) {
    int d = (pke[j] >> 8) & 255;
    int pos = atomicAdd(&cur[d], 1);
    adj[pos] = (short)j;
  }
  __syncthreads();

  // Phase 3: per-node accumulate (e global, h LDS) + finalize + x + readout
  const float rvx = root[2 * lane], rvy = root[2 * lane + 1];
  float2 mx = {-1e30f, -1e30f}, sm = {0.f, 0.f};
  for (int n = w; n < 256; n += NW) {
    float2 val = {0.f, 0.f};
    int b0 = off[n], b1 = off[n + 1];
    int k = b0;
    for (; k + 1 < b1; k += 2) {
      int j0 = adj[k], j1 = adj[k + 1];
      int s0 = pke[j0] & 255, s1 = pke[j1] & 255;
      float2 e0 = tof2(eg2[(size_t)j0 * 64]), e1 = tof2(eg2[(size_t)j1 * 64]);
      float2 h0 = tof2(*(const bf16x2*)&hl[s0 * 128 + 2 * lane]);
      float2 h1 = tof2(*(const bf16x2*)&hl[s1 * 128 + 2 * lane]);
      float c0 = coef[j0], c1 = coef[j1];
      val.x += c0 * fmaxf(h0.x + e0.x, 0.f) + c1 * fmaxf(h1.x + e1.x, 0.f);
      val.y += c0 * fmaxf(h0.y + e0.y, 0.f) + c1 * fmaxf(h1.y + e1.y, 0.f);
    }
    if (k < b1) {
      int j0 = adj[k];
      int s0 = pke[j0] & 255;
      float2 e0 = tof2(eg2[(size_t)j0 * 64]);
      float2 h0 = tof2(*(const bf16x2*)&hl[s0 * 128 + 2 * lane]);
      float c0 = coef[j0];
      val.x += c0 * fmaxf(h0.x + e0.x, 0.f);
      val.y += c0 * fmaxf(h0.y + e0.y, 0.f);
    }
    float inv = 1.f / ((float)cnts[n] + 1.f);
    float2 hv = tof2(*(const bf16x2*)&hl[n * 128 + 2 * lane]);
    float xvx = fmaxf(val.x + fmaxf(hv.x + rvx, 0.f) * inv, 0.f);
    float xvy = fmaxf(val.y + fmaxf(hv.y + rvy, 0.f) * inv, 0.f);
    xg2[(size_t)n * 64] = tob2(xvx, xvy);
    mx.x = fmaxf(mx.x, xvx); mx.y = fmaxf(mx.y, xvy);
    sm.x += xvx;             sm.y += xvy;
  }
  redm[w * 128 + 2 * lane]     = mx.x;
  redm[w * 128 + 2 * lane + 1] = mx.y;
  reds[w * 128 + 2 * lane]     = sm.x;
  reds[w * 128 + 2 * lane + 1] = sm.y;
  __syncthreads();

  if (t < 128) {
    float M = redm[t], S2 = reds[t];
#pragma unroll
    for (int k = 1; k < 16; ++k) {
      M = fmaxf(M, redm[k * 128 + t]);
      S2 += reds[k * 128 + t];
    }
    xs[g * 384 + t]       += M;
    xs[g * 384 + 128 + t] += S2 * (1.f / 256.f);
    xs[g * 384 + 256 + t] += S2;
  }
}

// ---------- MEGA hyperconv + top-k with FUSED z-GEMM:
//            z = e@Wh (MFMA -> global zbuf) + CSR + gather + eout + score +
//            register-bitonic sort + compaction. 1 block/graph, 1024 thr. ----------
template <int EG, int KEEP, int ENEW>
__global__ __launch_bounds__(1024, 4) void k_hyper_sort(const int* __restrict__ ei, int E,
                                                        __bf16* __restrict__ e,   // in: e; out: eout (in place)
                                                        const float* __restrict__ Wh,
                                                        const float* __restrict__ bias,
                                                        const float* __restrict__ wsc,
                                                        const float* __restrict__ bsc,
                                                        __bf16* __restrict__ zbuf,
                                                        int* __restrict__ ei_new,
                                                        __bf16* __restrict__ e_new,
                                                        float* __restrict__ ew) {
  constexpr int NW = 16;
  __shared__ bf16x8 Wl[4][8][64];             // 32 KB W fragments
  __shared__ __bf16 S[256 * 128];             // 64 KB (bf16)
  __shared__ int   pke[EG];
  __shared__ float as_[EG], ad_[EG], az_[EG];
  __shared__ float zsh[EG];
  __shared__ float Ssh[256];
  __shared__ int   cnt[256];
  __shared__ int   off[257];
  __shared__ int   cur[256];
  __shared__ int   wsum[4];
  __shared__ short adj[2 * EG];
  __shared__ float ls[512];
  __shared__ int   li[512];
  __shared__ int   sidx[512];
  const int g = blockIdx.x;
  const int t = threadIdx.x, w = t >> 6, lane = t & 63;
  const bf16x2* zg2 = (const bf16x2*)zbuf + (size_t)g * EG * 64 + lane;
  bf16x2* eo2 = (bf16x2*)e + (size_t)g * EG * 64 + lane;
  bf16x2* S2 = (bf16x2*)S;

  if (t < 256) { cnt[t] = 0; Ssh[t] = 0.f; }
  __syncthreads();

  // Phase 1: CSR counts + pke, W fragment staging, A-fragment preloads
  for (int j = t; j < EG; j += 1024) {
    int s = ei[g * EG + j] & 255, d = ei[E + g * EG + j] & 255;
    pke[j] = s | (d << 8);
    atomicAdd(&cnt[s], 1);
    atomicAdd(&cnt[d], 1);
  }
  {
    bf16x8* Wf = (bf16x8*)Wl;
    for (int q = t; q < 2048; q += 1024) {
      int ks = q >> 9, nt = (q >> 6) & 7, l = q & 63;
      int kk = ks * 32 + ((l >> 4) << 3);
      int nn = nt * 16 + (l & 15);
      const float* wp = Wh + (size_t)kk * 128 + nn;
      bf16x8 v;
#pragma unroll
      for (int b = 0; b < 8; ++b) v[b] = (__bf16)wp[(size_t)b * 128];
      Wf[q] = v;
    }
  }
  const int r0 = w * 32 + (lane & 15);
  const int r1 = r0 + 16;
  bf16x8 a0[4], a1[4];
  {
    bf16x8 zz = {};
    const __bf16* Ap0 = e + ((size_t)g * EG + r0) * 128 + ((lane >> 4) << 3);
    const __bf16* Ap1 = Ap0 + (size_t)16 * 128;
#pragma unroll
    for (int ks = 0; ks < 4; ++ks) {
      a0[ks] = (r0 < EG) ? *(const bf16x8*)(Ap0 + ks * 32) : zz;
      a1[ks] = (r1 < EG) ? *(const bf16x8*)(Ap1 + ks * 32) : zz;
    }
  }
  __syncthreads();

  // Phase 2: MFMA z = e @ Wh -> zbuf (rows < EG)
  {
    f32x4 acc0[8] = {}; f32x4 acc1[8] = {};
#pragma unroll
    for (int ks = 0; ks < 4; ++ks) {
#pragma unroll
      for (int nt = 0; nt < 8; ++nt) {
        bf16x8 b = Wl[ks][nt][lane];
        acc0[nt] = __builtin_amdgcn_mfma_f32_16x16x32_bf16(a0[ks], b, acc0[nt], 0, 0, 0);
        acc1[nt] = __builtin_amdgcn_mfma_f32_16x16x32_bf16(a1[ks], b, acc1[nt], 0, 0, 0);
      }
    }
    const int orow = w * 32 + ((lane >> 4) << 2);
    const int ocol = lane & 15;
#pragma unroll
    for (int nt = 0; nt < 8; ++nt) {
      __bf16* zp = zbuf + ((size_t)g * EG + orow) * 128 + nt * 16 + ocol;
#pragma unroll
      for (int r = 0; r < 4; ++r) {
        if (orow + r < EG)      zp[(size_t)r * 128]        = (__bf16)acc0[nt][r];
        if (orow + 16 + r < EG) zp[(size_t)(16 + r) * 128] = (__bf16)acc1[nt][r];
      }
    }
  }

  // Phase 3: per-edge gather constants
  for (int j = t; j < EG; j += 1024) {
    int p = pke[j];
    int s = p & 255, d = (p >> 8) & 255;
    int cs = cnt[s], cd = cnt[d];
    float bis  = (cs != 1) ? 1.f / (float)cs : 0.f;
    float bid_ = (cd != 1) ? 1.f / (float)cd : 0.f;
    float dinv = 1.f / (1.f + (cs != 1 ? 1.f : 0.f) + (cd != 1 ? 1.f : 0.f));
    as_[j] = dinv * bis;
    ad_[j] = dinv * bid_;
    az_[j] = dinv;
  }

  // wave-shuffle exclusive scan of cnt (2 barriers)
  {
    int v = 0;
    if (t < 256) {
      v = cnt[t];
#pragma unroll
      for (int d2 = 1; d2 < 64; d2 <<= 1) {
        int u = __shfl_up(v, d2);
        if (lane >= d2) v += u;
      }
      if (lane == 63) wsum[w] = v;
    }
    __syncthreads();
    if (t < 256) {
      int add = 0;
      if (w > 0) add += wsum[0];
      if (w > 1) add += wsum[1];
      if (w > 2) add += wsum[2];
      off[t + 1] = v + add;
      if (t == 0) off[0] = 0;
      cur[t] = v + add - cnt[t];
    }
    __syncthreads();
  }

  for (int j = t; j < EG; j += 1024) {
    int p = pke[j];
    int pos0 = atomicAdd(&cur[p & 255], 1);
    adj[pos0] = (short)j;
    int pos1 = atomicAdd(&cur[(p >> 8) & 255], 1);
    adj[pos1] = (short)j;
  }
  __syncthreads();

  // Phase 4: accumulate per node (z from zbuf, L2-warm; f32 regs, bf16 store)
  for (int n = w; n < 256; n += NW) {
    float2 val = {0.f, 0.f};
    int b0 = off[n], b1 = off[n + 1];
    int k = b0;
    for (; k + 1 < b1; k += 2) {
      float2 a = tof2(zg2[(size_t)adj[k] * 64]);
      float2 b = tof2(zg2[(size_t)adj[k + 1] * 64]);
      val.x += a.x + b.x;
      val.y += a.y + b.y;
    }
    if (k < b1) {
      float2 a = tof2(zg2[(size_t)adj[k] * 64]);
      val.x += a.x; val.y += a.y;
    }
    S2[n * 64 + lane] = tob2(val.x, val.y);
  }
  __syncthreads();

  // Phase 5: gather + eout(bf16, in-place over e) + score dot -> zsh
  const float bbx = bias[2 * lane], bby = bias[2 * lane + 1];
  const float wvx = wsc[2 * lane],  wvy = wsc[2 * lane + 1];
  for (int j = w; j < EG; j += NW) {
    int p = pke[j];
    int s = p & 255, d = (p >> 8) & 255;
    float a_s = as_[j], a_d = ad_[j], a_z = az_[j];
    float2 Sv = tof2(S2[s * 64 + lane]);
    float2 Dv = tof2(S2[d * 64 + lane]);
    float2 zv = tof2(zg2[(size_t)j * 64]);
    float ox = fmaxf(a_s * Sv.x + a_d * Dv.x + a_z * zv.x + bbx, 0.f);
    float oy = fmaxf(a_s * Sv.y + a_d * Dv.y + a_z * zv.y + bby, 0.f);
    eo2[(size_t)j * 64] = tob2(ox, oy);
    float part = ox * wvx + oy * wvy;
#pragma unroll
    for (int offs = 32; offs > 0; offs >>= 1) part += __shfl_xor(part, offs);
    if (lane == 0) zsh[j] = part;
  }
  __syncthreads();

  // Phase 6: scalar hyperconv on scores
  if (t < EG) {
    float v = zsh[t];
    atomicAdd(&Ssh[pke[t] & 255], v);
    atomicAdd(&Ssh[(pke[t] >> 8) & 255], v);
  }
  __syncthreads();

  // Phase 7: score finalize + bitonic sort
  float sc = -INFINITY; int idx = 0x7FFFFFFF;
  if (t < EG) {
    int p = pke[t];
    int sn = p & 255, dn = (p >> 8) & 255;
    sc = tanhf(as_[t] * Ssh[sn] + ad_[t] * Ssh[dn] + az_[t] * zsh[t] + bsc[0]);
    idx = t;
  }
#pragma unroll
  for (int k = 2; k <= 512; k <<= 1) {
#pragma unroll
    for (int j = k >> 1; j > 0; j >>= 1) {
      if (j < 64) {
        if (t < 512) {
          float ps = __shfl_xor(sc, j);
          int   pi = __shfl_xor(idx, j);
          bool ownBetter = (sc > ps) || (sc == ps && idx < pi);
          bool lower = ((t & j) == 0);
          bool desc = ((t & k) == 0);
          bool keep = desc ? (lower ? ownBetter : !ownBetter)
                           : (lower ? !ownBetter : ownBetter);
          if (!keep) { sc = ps; idx = pi; }
        }
      } else {
        if (t < 512) { ls[t] = sc; li[t] = idx; }
        __syncthreads();
        if (t < 512) {
          float ps = ls[t ^ j];
          int   pi = li[t ^ j];
          bool ownBetter = (sc > ps) || (sc == ps && idx < pi);
          bool lower = ((t & j) == 0);
          bool desc = ((t & k) == 0);
          bool keep = desc ? (lower ? ownBetter : !ownBetter)
                           : (lower ? !ownBetter : ownBetter);
          if (!keep) { sc = ps; idx = pi; }
        }
        __syncthreads();
      }
    }
  }

  if (t < 512) sidx[t] = idx;
  if (t < KEEP) {
    int oldp = g * EG + idx;
    int newp = g * KEEP + t;
    ei_new[newp]        = ei[oldp];
    ei_new[ENEW + newp] = ei[E + oldp];
    ew[newp] = fminf(fmaxf(sc, 0.f), 1.f);
  }
  __syncthreads();

  // Phase 8: compaction (reads eout rows this block wrote; barrier-ordered)
  const float4* src = (const float4*)e;
  float4* dst = (float4*)e_new;
  for (int q = t; q < KEEP * 16; q += 1024) {
    int j2 = q >> 4, c = q & 15;
    dst[((size_t)g * KEEP + j2) * 16 + c] = src[((size_t)g * EG + sidx[j2]) * 16 + c];
  }
}

// ---------- final MLP ----------
__global__ __launch_bounds__(128) void k_mlp(const float* __restrict__ xs,
                                             const float* __restrict__ Wc1, const float* __restrict__ bc1,
                                             const float* __restrict__ Wc2, const float* __restrict__ bc2,
                                             const float* __restrict__ Wc3, const float* __restrict__ bc3,
                                             float* __restrict__ out) {
  __shared__ float row[384];
  __shared__ float h1[128];
  __shared__ float h2[64];
  int g = blockIdx.x, t = threadIdx.x;
  for (int i = t; i < 384; i += 128) row[i] = xs[g * 384 + i];
  __syncthreads();
  float a = bc1[t];
  for (int k = 0; k < 384; ++k) a += row[k] * Wc1[k * 128 + t];
  h1[t] = fmaxf(a, 0.f);
  __syncthreads();
  if (t < 64) {
    float b = bc2[t];
    for (int k = 0; k < 128; ++k) b += h1[k] * Wc2[k * 64 + t];
    h2[t] = fmaxf(b, 0.f);
  }
  __syncthreads();
  float o = bc3[t];
  for (int k = 0; k < 64; ++k) o += h2[k] * Wc3[k * 128 + t];
  out[g * 128 + t] = o;
}

extern "C" void kernel_launch(void* const* d_in, const int* in_sizes, int n_in,
                              void* d_out, int out_size, void* d_ws, size_t ws_size,
                              hipStream_t stream) {
  (void)in_sizes; (void)n_in; (void)out_size; (void)ws_size;
  const int*   x_idx  = (const int*)d_in[0];
  const int*   b_idx  = (const int*)d_in[1];
  const int*   ei0    = (const int*)d_in[2];
  const float* atom_t = (const float*)d_in[4];
  const float* bond_t = (const float*)d_in[5];
  const float* W_gcn  = (const float*)d_in[6];
  const float* b_gcn  = (const float*)d_in[7];
  const float* root   = (const float*)d_in[8];
  const float* W_hyp  = (const float*)d_in[9];
  const float* b_hyp  = (const float*)d_in[10];
  const float* W_sc   = (const float*)d_in[11];
  const float* b_sc   = (const float*)d_in[12];
  const float* Wc1    = (const float*)d_in[13];
  const float* bc1_   = (const float*)d_in[14];
  const float* Wc2    = (const float*)d_in[15];
  const float* bc2_   = (const float*)d_in[16];
  const float* Wc3    = (const float*)d_in[17];
  const float* bc3_   = (const float*)d_in[18];
  float* out = (float*)d_out;

  // workspace layout: bf16 activations first, then f32 scalars
  __bf16* x    = (__bf16*)d_ws;
  __bf16* eA   = x    + (size_t)NTOT * D;
  __bf16* eB   = eA   + (size_t)E0 * D;
  __bf16* zbuf = eB   + (size_t)E0 * D;
  float* ew  = (float*)(zbuf + (size_t)E0 * D);
  float* xs  = ew + E0;
  int*   eiB  = (int*)(xs + BG * 384);
  int*   eiA2 = eiB + 2 * E0;

  hipMemsetAsync(xs, 0, BG * 384 * 4, stream);
  k_embed_x<<<NTOT * 32 / 256, 256, 0, stream>>>(x_idx, atom_t, x);
  k_embed_e<<<E0 * 32 / 256, 256, 0, stream>>>(b_idx, bond_t, eA);

  // ---- layer 0 ----
  k_gcn_fused<EG0, false><<<BG, 1024, 0, stream>>>(ei0, E0, eA, W_gcn, b_gcn, nullptr, root, x, xs);
  k_hyper_sort<EG0, KP0, E1><<<BG, 1024, 0, stream>>>(ei0, E0, eA, W_hyp, b_hyp, W_sc, b_sc, zbuf, eiB, eB, ew);

  // ---- layer 1 ----
  k_gcn_fused<KP0, true><<<BG, 1024, 0, stream>>>(eiB, E1, eB, W_gcn + D * D, b_gcn + D, ew, root + D, x, xs);
  k_hyper_sort<KP0, KP1, E2><<<BG, 1024, 0, stream>>>(eiB, E1, eB, W_hyp + D * D, b_hyp + D, W_sc + D, b_sc + 1, zbuf, eiA2, eA, ew);

  // ---- layer 2 ----
  k_gcn_fused<KP1, true><<<BG, 1024, 0, stream>>>(eiA2, E2, eA, W_gcn + 2 * D * D, b_gcn + 2 * D, ew, root + 2 * D, x, xs);

  k_mlp<<<BG, 128, 0, stream>>>(xs, Wc1, bc1_, Wc2, bc2_, Wc3, bc3_, out);
}

// Round 19
// 224.319 us; speedup vs baseline: 1.1979x; 1.0034x over previous
//
#include <hip/hip_runtime.h>
#include <hip/hip_bf16.h>
#include <math.h>

constexpr int NTOT = 65536;
constexpr int D    = 128;
constexpr int BG   = 256;
constexpr int E0 = 131072, E1 = 104960, E2 = 83968;
constexpr int EG0 = 512;
constexpr int KP0 = 410, KP1 = 328;

typedef __bf16 bf16x8 __attribute__((ext_vector_type(8)));
typedef __bf16 bf16x4 __attribute__((ext_vector_type(4)));
typedef __bf16 bf16x2 __attribute__((ext_vector_type(2)));
typedef float  f32x4  __attribute__((ext_vector_type(4)));

__device__ __forceinline__ float2 tof2(bf16x2 v) {
  return make_float2((float)v[0], (float)v[1]);
}
__device__ __forceinline__ bf16x2 tob2(float ax, float ay) {
  bf16x2 r; r[0] = (__bf16)ax; r[1] = (__bf16)ay; return r;
}

// ---------- embeddings (f32 tables -> bf16 activations) ----------
__global__ __launch_bounds__(256) void k_embed_x(const int* __restrict__ xi,
                                                 const float* __restrict__ tab,
                                                 __bf16* __restrict__ x) {
  int t = blockIdx.x * 256 + threadIdx.x;      // NTOT*32 threads
  int v = t >> 5, q = (t & 31) << 2;
  float4 s = {0.f, 0.f, 0.f, 0.f};
#pragma unroll
  for (int j = 0; j < 9; ++j) {
    int r = xi[v * 9 + j];
    float4 a = *(const float4*)&tab[r * D + q];
    s.x += a.x; s.y += a.y; s.z += a.z; s.w += a.w;
  }
  bf16x4 o; o[0] = (__bf16)s.x; o[1] = (__bf16)s.y; o[2] = (__bf16)s.z; o[3] = (__bf16)s.w;
  *(bf16x4*)&x[(size_t)v * D + q] = o;
}

__global__ __launch_bounds__(256) void k_embed_e(const int* __restrict__ bi,
                                                 const float* __restrict__ tab,
                                                 __bf16* __restrict__ e) {
  int t = blockIdx.x * 256 + threadIdx.x;      // E0*32 threads
  int i = t >> 5, q = (t & 31) << 2;
  float4 s = {0.f, 0.f, 0.f, 0.f};
#pragma unroll
  for (int j = 0; j < 3; ++j) {
    int r = bi[i * 3 + j];
    float4 a = *(const float4*)&tab[r * D + q];
    s.x += a.x; s.y += a.y; s.z += a.z; s.w += a.w;
  }
  bf16x4 o; o[0] = (__bf16)s.x; o[1] = (__bf16)s.y; o[2] = (__bf16)s.z; o[3] = (__bf16)s.w;
  *(bf16x4*)&e[(size_t)i * D + q] = o;
}

// ---------- MEGA GCN layer: fused h = x@Wg + b (MFMA into LDS) + CSR message
//            passing + finalize + in-place x update + readout.
//            1 block/graph, 1024 thr (16 waves x 16 rows). ----------
template <int EG, bool HAS_EW>
__global__ __launch_bounds__(1024, 4) void k_gcn_fused(const int* __restrict__ ei, int E,
                                                       const __bf16* __restrict__ e,
                                                       const float* __restrict__ Wg,
                                                       const float* __restrict__ bg,
                                                       const float* __restrict__ ew,
                                                       const float* __restrict__ root,
                                                       __bf16* __restrict__ x,
                                                       float* __restrict__ xs) {
  constexpr int NW = 16;
  __shared__ bf16x8 Wl[4][8][64];             // 32 KB W fragments
  __shared__ __bf16 hl[256 * 128];            // 64 KB h tile
  __shared__ int   pke[EG];
  __shared__ float coef[EG];
  __shared__ int   cnts[256];
  __shared__ int   cntd[256];
  __shared__ int   off[257];
  __shared__ int   cur[256];
  __shared__ int   wsum[4];
  __shared__ short adj[EG];
  __shared__ float redm[16 * 128], reds[16 * 128];   // 16 KB
  const int g = blockIdx.x;
  const int t = threadIdx.x, w = t >> 6, lane = t & 63;
  const bf16x2* eg2 = (const bf16x2*)e + (size_t)g * EG * 64 + lane;
  bf16x2* xg2 = (bf16x2*)x + (size_t)g * 256 * 64 + lane;

  if (t < 256) { cnts[t] = 0; cntd[t] = 0; }
  __syncthreads();

  // Phase 1: CSR counts + packed indices, and W fragment staging (independent)
  for (int j = t; j < EG; j += 1024) {
    int s = ei[g * EG + j] & 255, d = ei[E + g * EG + j] & 255;
    pke[j] = s | (d << 8);
    atomicAdd(&cnts[s], 1);
    atomicAdd(&cntd[d], 1);
  }
  {
    bf16x8* Wf = (bf16x8*)Wl;
    for (int q = t; q < 2048; q += 1024) {
      int ks = q >> 9, nt = (q >> 6) & 7, l = q & 63;
      int kk = ks * 32 + ((l >> 4) << 3);
      int nn = nt * 16 + (l & 15);
      const float* wp = Wg + (size_t)kk * 128 + nn;
      bf16x8 v;
#pragma unroll
      for (int b = 0; b < 8; ++b) v[b] = (__bf16)wp[(size_t)b * 128];
      Wf[q] = v;
    }
  }
  __syncthreads();

  // Phase 2a: MFMA h = x@Wg + bg for this graph's 256 rows -> LDS hl
  {
    const int r0 = w * 16 + (lane & 15);
    const __bf16* Ap = x + ((size_t)(g * 256 + r0)) * 128 + ((lane >> 4) << 3);
    bf16x8 af[4];
#pragma unroll
    for (int ks = 0; ks < 4; ++ks) af[ks] = *(const bf16x8*)(Ap + ks * 32);
    f32x4 acc[8] = {};
#pragma unroll
    for (int ks = 0; ks < 4; ++ks) {
#pragma unroll
      for (int nt = 0; nt < 8; ++nt) {
        acc[nt] = __builtin_amdgcn_mfma_f32_16x16x32_bf16(af[ks], Wl[ks][nt][lane], acc[nt], 0, 0, 0);
      }
    }
    const int lrow = w * 16 + ((lane >> 4) << 2);
    const int ocol = lane & 15;
#pragma unroll
    for (int nt = 0; nt < 8; ++nt) {
      float bb = bg[nt * 16 + ocol];
#pragma unroll
      for (int r = 0; r < 4; ++r)
        hl[(lrow + r) * 128 + nt * 16 + ocol] = (__bf16)(acc[nt][r] + bb);
    }
  }

  // Phase 2b: per-edge coefficient
  for (int j = t; j < EG; j += 1024) {
    int p = pke[j];
    int s = p & 255, d = (p >> 8) & 255;
    float c = rsqrtf(((float)cnts[s] + 1.f) * ((float)cnts[d] + 1.f));
    if (HAS_EW) c *= ew[g * EG + j];
    coef[j] = c;
  }

  // Phase 2c: wave-shuffle exclusive scan of cntd (2 barriers)
  {
    int v = 0;
    if (t < 256) {
      v = cntd[t];
#pragma unroll
      for (int d2 = 1; d2 < 64; d2 <<= 1) {
        int u = __shfl_up(v, d2);
        if (lane >= d2) v += u;
      }
      if (lane == 63) wsum[w] = v;
    }
    __syncthreads();
    if (t < 256) {
      int add = 0;
      if (w > 0) add += wsum[0];
      if (w > 1) add += wsum[1];
      if (w > 2) add += wsum[2];
      off[t + 1] = v + add;
      if (t == 0) off[0] = 0;
      cur[t] = v + add - cntd[t];
    }
    __syncthreads();
  }

  for (int j = t; j < EG; j += 1024) {
    int d = (pke[j] >> 8) & 255;
    int pos = atomicAdd(&cur[d], 1);
    adj[pos] = (short)j;
  }
  __syncthreads();

  // Phase 3: per-node accumulate (e global, h LDS) + finalize + x + readout
  const float rvx = root[2 * lane], rvy = root[2 * lane + 1];
  float2 mx = {-1e30f, -1e30f}, sm = {0.f, 0.f};
  for (int n = w; n < 256; n += NW) {
    float2 val = {0.f, 0.f};
    int b0 = off[n], b1 = off[n + 1];
    int k = b0;
    for (; k + 1 < b1; k += 2) {
      int j0 = adj[k], j1 = adj[k + 1];
      int s0 = pke[j0] & 255, s1 = pke[j1] & 255;
      float2 e0 = tof2(eg2[(size_t)j0 * 64]), e1 = tof2(eg2[(size_t)j1 * 64]);
      float2 h0 = tof2(*(const bf16x2*)&hl[s0 * 128 + 2 * lane]);
      float2 h1 = tof2(*(const bf16x2*)&hl[s1 * 128 + 2 * lane]);
      float c0 = coef[j0], c1 = coef[j1];
      val.x += c0 * fmaxf(h0.x + e0.x, 0.f) + c1 * fmaxf(h1.x + e1.x, 0.f);
      val.y += c0 * fmaxf(h0.y + e0.y, 0.f) + c1 * fmaxf(h1.y + e1.y, 0.f);
    }
    if (k < b1) {
      int j0 = adj[k];
      int s0 = pke[j0] & 255;
      float2 e0 = tof2(eg2[(size_t)j0 * 64]);
      float2 h0 = tof2(*(const bf16x2*)&hl[s0 * 128 + 2 * lane]);
      float c0 = coef[j0];
      val.x += c0 * fmaxf(h0.x + e0.x, 0.f);
      val.y += c0 * fmaxf(h0.y + e0.y, 0.f);
    }
    float inv = 1.f / ((float)cnts[n] + 1.f);
    float2 hv = tof2(*(const bf16x2*)&hl[n * 128 + 2 * lane]);
    float xvx = fmaxf(val.x + fmaxf(hv.x + rvx, 0.f) * inv, 0.f);
    float xvy = fmaxf(val.y + fmaxf(hv.y + rvy, 0.f) * inv, 0.f);
    xg2[(size_t)n * 64] = tob2(xvx, xvy);
    mx.x = fmaxf(mx.x, xvx); mx.y = fmaxf(mx.y, xvy);
    sm.x += xvx;             sm.y += xvy;
  }
  redm[w * 128 + 2 * lane]     = mx.x;
  redm[w * 128 + 2 * lane + 1] = mx.y;
  reds[w * 128 + 2 * lane]     = sm.x;
  reds[w * 128 + 2 * lane + 1] = sm.y;
  __syncthreads();

  if (t < 128) {
    float M = redm[t], S2 = reds[t];
#pragma unroll
    for (int k = 1; k < 16; ++k) {
      M = fmaxf(M, redm[k * 128 + t]);
      S2 += reds[k * 128 + t];
    }
    xs[g * 384 + t]       += M;
    xs[g * 384 + 128 + t] += S2 * (1.f / 256.f);
    xs[g * 384 + 256 + t] += S2;
  }
}

// ---------- MEGA hyperconv + top-k, zbuf-free (linearity: S = Esum @ Wh):
//            CSR + Esum accumulate (LDS) + S-MFMA (in-place LDS) +
//            z-MFMA with fused gather/eout/score + sort + compaction.
//            1 block/graph, 1024 thr. ----------
template <int EG, int KEEP, int ENEW>
__global__ __launch_bounds__(1024, 4) void k_hyper_sort(const int* __restrict__ ei, int E,
                                                        __bf16* __restrict__ e,   // in: e; out: eout (in place)
                                                        const float* __restrict__ Wh,
                                                        const float* __restrict__ bias,
                                                        const float* __restrict__ wsc,
                                                        const float* __restrict__ bsc,
                                                        int* __restrict__ ei_new,
                                                        __bf16* __restrict__ e_new,
                                                        float* __restrict__ ew) {
  constexpr int NW = 16;
  __shared__ bf16x8 Wl[4][8][64];             // 32 KB W fragments
  __shared__ __bf16 ES[256 * 128];            // 64 KB: Esum, then S (in place)
  __shared__ int   pke[EG];
  __shared__ float as_[EG], ad_[EG], az_[EG];
  __shared__ float zsh[EG];
  __shared__ float Ssh[256];
  __shared__ int   cnt[256];
  __shared__ int   off[257];
  __shared__ int   cur[256];
  __shared__ int   wsum[4];
  __shared__ short adj[2 * EG];
  __shared__ float ls[512];
  __shared__ int   li[512];
  __shared__ int   sidx[512];
  const int g = blockIdx.x;
  const int t = threadIdx.x, w = t >> 6, lane = t & 63;
  const int hi = lane >> 4, lo = lane & 15;
  const bf16x2* eg2 = (const bf16x2*)e + (size_t)g * EG * 64 + lane;
  bf16x2* ES2 = (bf16x2*)ES;

  if (t < 256) { cnt[t] = 0; Ssh[t] = 0.f; }
  __syncthreads();

  // Phase 1: CSR counts + pke + W fragment staging
  for (int j = t; j < EG; j += 1024) {
    int s = ei[g * EG + j] & 255, d = ei[E + g * EG + j] & 255;
    pke[j] = s | (d << 8);
    atomicAdd(&cnt[s], 1);
    atomicAdd(&cnt[d], 1);
  }
  {
    bf16x8* Wf = (bf16x8*)Wl;
    for (int q = t; q < 2048; q += 1024) {
      int ks = q >> 9, nt = (q >> 6) & 7, l = q & 63;
      int kk = ks * 32 + ((l >> 4) << 3);
      int nn = nt * 16 + (l & 15);
      const float* wp = Wh + (size_t)kk * 128 + nn;
      bf16x8 v;
#pragma unroll
      for (int b = 0; b < 8; ++b) v[b] = (__bf16)wp[(size_t)b * 128];
      Wf[q] = v;
    }
  }
  __syncthreads();

  // Phase 2: per-edge gather constants
  for (int j = t; j < EG; j += 1024) {
    int p = pke[j];
    int s = p & 255, d = (p >> 8) & 255;
    int cs = cnt[s], cd = cnt[d];
    float bis  = (cs != 1) ? 1.f / (float)cs : 0.f;
    float bid_ = (cd != 1) ? 1.f / (float)cd : 0.f;
    float dinv = 1.f / (1.f + (cs != 1 ? 1.f : 0.f) + (cd != 1 ? 1.f : 0.f));
    as_[j] = dinv * bis;
    ad_[j] = dinv * bid_;
    az_[j] = dinv;
  }

  // wave-shuffle exclusive scan of cnt (2 barriers)
  {
    int v = 0;
    if (t < 256) {
      v = cnt[t];
#pragma unroll
      for (int d2 = 1; d2 < 64; d2 <<= 1) {
        int u = __shfl_up(v, d2);
        if (lane >= d2) v += u;
      }
      if (lane == 63) wsum[w] = v;
    }
    __syncthreads();
    if (t < 256) {
      int add = 0;
      if (w > 0) add += wsum[0];
      if (w > 1) add += wsum[1];
      if (w > 2) add += wsum[2];
      off[t + 1] = v + add;
      if (t == 0) off[0] = 0;
      cur[t] = v + add - cnt[t];
    }
    __syncthreads();
  }

  for (int j = t; j < EG; j += 1024) {
    int p = pke[j];
    int pos0 = atomicAdd(&cur[p & 255], 1);
    adj[pos0] = (short)j;
    int pos1 = atomicAdd(&cur[(p >> 8) & 255], 1);
    adj[pos1] = (short)j;
  }
  __syncthreads();

  // Phase 3: Esum[n] = sum of incident e rows (f32 regs, bf16 LDS store)
  for (int n = w; n < 256; n += NW) {
    float2 val = {0.f, 0.f};
    int b0 = off[n], b1 = off[n + 1];
    int k = b0;
    for (; k + 1 < b1; k += 2) {
      float2 a = tof2(eg2[(size_t)adj[k] * 64]);
      float2 b = tof2(eg2[(size_t)adj[k + 1] * 64]);
      val.x += a.x + b.x;
      val.y += a.y + b.y;
    }
    if (k < b1) {
      float2 a = tof2(eg2[(size_t)adj[k] * 64]);
      val.x += a.x; val.y += a.y;
    }
    ES2[n * 64 + lane] = tob2(val.x, val.y);
  }
  __syncthreads();

  // Phase 4: S = Esum @ Wh (in-place in ES; each wave owns its 16-row tile)
  {
    const int mr = w * 16 + lo;
    const __bf16* Ep = ES + mr * 128 + (hi << 3);
    bf16x8 ef[4];
#pragma unroll
    for (int ks = 0; ks < 4; ++ks) ef[ks] = *(const bf16x8*)(Ep + ks * 32);
    f32x4 acc[8] = {};
#pragma unroll
    for (int ks = 0; ks < 4; ++ks) {
#pragma unroll
      for (int nt = 0; nt < 8; ++nt) {
        acc[nt] = __builtin_amdgcn_mfma_f32_16x16x32_bf16(ef[ks], Wl[ks][nt][lane], acc[nt], 0, 0, 0);
      }
    }
    const int lrow = w * 16 + (hi << 2);
#pragma unroll
    for (int nt = 0; nt < 8; ++nt) {
#pragma unroll
      for (int r = 0; r < 4; ++r)
        ES[(lrow + r) * 128 + nt * 16 + lo] = (__bf16)acc[nt][r];
    }
  }
  __syncthreads();

  // Phase 5: z = e @ Wh (MFMA, z stays in registers) + fused gather/eout/score
  {
    const int r0 = w * 32 + lo;
    const int r1 = r0 + 16;
    bf16x8 a0[4], a1[4];
    {
      bf16x8 zz = {};
      const __bf16* Ap0 = e + ((size_t)g * EG + r0) * 128 + (hi << 3);
      const __bf16* Ap1 = Ap0 + (size_t)16 * 128;
#pragma unroll
      for (int ks = 0; ks < 4; ++ks) {
        a0[ks] = (r0 < EG) ? *(const bf16x8*)(Ap0 + ks * 32) : zz;
        a1[ks] = (r1 < EG) ? *(const bf16x8*)(Ap1 + ks * 32) : zz;
      }
    }
    f32x4 acc0[8] = {}; f32x4 acc1[8] = {};
#pragma unroll
    for (int ks = 0; ks < 4; ++ks) {
#pragma unroll
      for (int nt = 0; nt < 8; ++nt) {
        bf16x8 b = Wl[ks][nt][lane];
        acc0[nt] = __builtin_amdgcn_mfma_f32_16x16x32_bf16(a0[ks], b, acc0[nt], 0, 0, 0);
        acc1[nt] = __builtin_amdgcn_mfma_f32_16x16x32_bf16(a1[ks], b, acc1[nt], 0, 0, 0);
      }
    }
    // epilogue: per-lane rows row0+r (acc0) and row1+r (acc1), col nt*16+lo
    const int row0 = w * 32 + (hi << 2);
    const int row1 = row0 + 16;
    float wv[8], bb[8];
#pragma unroll
    for (int nt = 0; nt < 8; ++nt) {
      wv[nt] = wsc[nt * 16 + lo];
      bb[nt] = bias[nt * 16 + lo];
    }
    float as0[4], ad0[4], az0[4], as1[4], ad1[4], az1[4];
    int ps0[4], pd0[4], ps1[4], pd1[4];
#pragma unroll
    for (int r = 0; r < 4; ++r) {
      int ra = row0 + r;
      if (ra < EG) {
        int p = pke[ra];
        ps0[r] = (p & 255) * 128; pd0[r] = ((p >> 8) & 255) * 128;
        as0[r] = as_[ra]; ad0[r] = ad_[ra]; az0[r] = az_[ra];
      } else { ps0[r] = 0; pd0[r] = 0; as0[r] = 0.f; ad0[r] = 0.f; az0[r] = 0.f; }
      int rb = row1 + r;
      if (rb < EG) {
        int p = pke[rb];
        ps1[r] = (p & 255) * 128; pd1[r] = ((p >> 8) & 255) * 128;
        as1[r] = as_[rb]; ad1[r] = ad_[rb]; az1[r] = az_[rb];
      } else { ps1[r] = 0; pd1[r] = 0; as1[r] = 0.f; ad1[r] = 0.f; az1[r] = 0.f; }
    }
    float sp0[4] = {0.f, 0.f, 0.f, 0.f};
    float sp1[4] = {0.f, 0.f, 0.f, 0.f};
#pragma unroll
    for (int nt = 0; nt < 8; ++nt) {
      int col = nt * 16 + lo;
#pragma unroll
      for (int r = 0; r < 4; ++r) {
        if (row0 + r < EG) {
          float o = fmaxf(as0[r] * (float)ES[ps0[r] + col] + ad0[r] * (float)ES[pd0[r] + col]
                          + az0[r] * acc0[nt][r] + bb[nt], 0.f);
          e[((size_t)g * EG + row0 + r) * 128 + col] = (__bf16)o;
          sp0[r] += o * wv[nt];
        }
        if (row1 + r < EG) {
          float o = fmaxf(as1[r] * (float)ES[ps1[r] + col] + ad1[r] * (float)ES[pd1[r] + col]
                          + az1[r] * acc1[nt][r] + bb[nt], 0.f);
          e[((size_t)g * EG + row1 + r) * 128 + col] = (__bf16)o;
          sp1[r] += o * wv[nt];
        }
      }
    }
    // reduce score partials across the 16-lane (lo) group
#pragma unroll
    for (int offs = 1; offs < 16; offs <<= 1) {
#pragma unroll
      for (int r = 0; r < 4; ++r) {
        sp0[r] += __shfl_xor(sp0[r], offs);
        sp1[r] += __shfl_xor(sp1[r], offs);
      }
    }
    if (lo == 0) {
#pragma unroll
      for (int r = 0; r < 4; ++r) {
        if (row0 + r < EG) zsh[row0 + r] = sp0[r];
        if (row1 + r < EG) zsh[row1 + r] = sp1[r];
      }
    }
  }
  __syncthreads();

  // Phase 6: scalar hyperconv on scores
  if (t < EG) {
    float v = zsh[t];
    atomicAdd(&Ssh[pke[t] & 255], v);
    atomicAdd(&Ssh[(pke[t] >> 8) & 255], v);
  }
  __syncthreads();

  // Phase 7: score finalize + bitonic sort
  float sc = -INFINITY; int idx = 0x7FFFFFFF;
  if (t < EG) {
    int p = pke[t];
    int sn = p & 255, dn = (p >> 8) & 255;
    sc = tanhf(as_[t] * Ssh[sn] + ad_[t] * Ssh[dn] + az_[t] * zsh[t] + bsc[0]);
    idx = t;
  }
#pragma unroll
  for (int k = 2; k <= 512; k <<= 1) {
#pragma unroll
    for (int j = k >> 1; j > 0; j >>= 1) {
      if (j < 64) {
        if (t < 512) {
          float ps = __shfl_xor(sc, j);
          int   pi = __shfl_xor(idx, j);
          bool ownBetter = (sc > ps) || (sc == ps && idx < pi);
          bool lower = ((t & j) == 0);
          bool desc = ((t & k) == 0);
          bool keep = desc ? (lower ? ownBetter : !ownBetter)
                           : (lower ? !ownBetter : ownBetter);
          if (!keep) { sc = ps; idx = pi; }
        }
      } else {
        if (t < 512) { ls[t] = sc; li[t] = idx; }
        __syncthreads();
        if (t < 512) {
          float ps = ls[t ^ j];
          int   pi = li[t ^ j];
          bool ownBetter = (sc > ps) || (sc == ps && idx < pi);
          bool lower = ((t & j) == 0);
          bool desc = ((t & k) == 0);
          bool keep = desc ? (lower ? ownBetter : !ownBetter)
                           : (lower ? !ownBetter : ownBetter);
          if (!keep) { sc = ps; idx = pi; }
        }
        __syncthreads();
      }
    }
  }

  if (t < 512) sidx[t] = idx;
  if (t < KEEP) {
    int oldp = g * EG + idx;
    int newp = g * KEEP + t;
    ei_new[newp]        = ei[oldp];
    ei_new[ENEW + newp] = ei[E + oldp];
    ew[newp] = fminf(fmaxf(sc, 0.f), 1.f);
  }
  __syncthreads();

  // Phase 8: compaction (reads eout rows this block wrote; barrier-ordered)
  const float4* src = (const float4*)e;
  float4* dst = (float4*)e_new;
  for (int q = t; q < KEEP * 16; q += 1024) {
    int j2 = q >> 4, c = q & 15;
    dst[((size_t)g * KEEP + j2) * 16 + c] = src[((size_t)g * EG + sidx[j2]) * 16 + c];
  }
}

// ---------- final MLP ----------
__global__ __launch_bounds__(128) void k_mlp(const float* __restrict__ xs,
                                             const float* __restrict__ Wc1, const float* __restrict__ bc1,
                                             const float* __restrict__ Wc2, const float* __restrict__ bc2,
                                             const float* __restrict__ Wc3, const float* __restrict__ bc3,
                                             float* __restrict__ out) {
  __shared__ float row[384];
  __shared__ float h1[128];
  __shared__ float h2[64];
  int g = blockIdx.x, t = threadIdx.x;
  for (int i = t; i < 384; i += 128) row[i] = xs[g * 384 + i];
  __syncthreads();
  float a = bc1[t];
  for (int k = 0; k < 384; ++k) a += row[k] * Wc1[k * 128 + t];
  h1[t] = fmaxf(a, 0.f);
  __syncthreads();
  if (t < 64) {
    float b = bc2[t];
    for (int k = 0; k < 128; ++k) b += h1[k] * Wc2[k * 64 + t];
    h2[t] = fmaxf(b, 0.f);
  }
  __syncthreads();
  float o = bc3[t];
  for (int k = 0; k < 64; ++k) o += h2[k] * Wc3[k * 128 + t];
  out[g * 128 + t] = o;
}

extern "C" void kernel_launch(void* const* d_in, const int* in_sizes, int n_in,
                              void* d_out, int out_size, void* d_ws, size_t ws_size,
                              hipStream_t stream) {
  (void)in_sizes; (void)n_in; (void)out_size; (void)ws_size;
  const int*   x_idx  = (const int*)d_in[0];
  const int*   b_idx  = (const int*)d_in[1];
  const int*   ei0    = (const int*)d_in[2];
  const float* atom_t = (const float*)d_in[4];
  const float* bond_t = (const float*)d_in[5];
  const float* W_gcn  = (const float*)d_in[6];
  const float* b_gcn  = (const float*)d_in[7];
  const float* root   = (const float*)d_in[8];
  const float* W_hyp  = (const float*)d_in[9];
  const float* b_hyp  = (const float*)d_in[10];
  const float* W_sc   = (const float*)d_in[11];
  const float* b_sc   = (const float*)d_in[12];
  const float* Wc1    = (const float*)d_in[13];
  const float* bc1_   = (const float*)d_in[14];
  const float* Wc2    = (const float*)d_in[15];
  const float* bc2_   = (const float*)d_in[16];
  const float* Wc3    = (const float*)d_in[17];
  const float* bc3_   = (const float*)d_in[18];
  float* out = (float*)d_out;

  // workspace layout: bf16 activations first, then f32 scalars
  __bf16* x    = (__bf16*)d_ws;
  __bf16* eA   = x    + (size_t)NTOT * D;
  __bf16* eB   = eA   + (size_t)E0 * D;
  float* ew  = (float*)(eB + (size_t)E0 * D);
  float* xs  = ew + E0;
  int*   eiB  = (int*)(xs + BG * 384);
  int*   eiA2 = eiB + 2 * E0;

  hipMemsetAsync(xs, 0, BG * 384 * 4, stream);
  k_embed_x<<<NTOT * 32 / 256, 256, 0, stream>>>(x_idx, atom_t, x);
  k_embed_e<<<E0 * 32 / 256, 256, 0, stream>>>(b_idx, bond_t, eA);

  // ---- layer 0 ----
  k_gcn_fused<EG0, false><<<BG, 1024, 0, stream>>>(ei0, E0, eA, W_gcn, b_gcn, nullptr, root, x, xs);
  k_hyper_sort<EG0, KP0, E1><<<BG, 1024, 0, stream>>>(ei0, E0, eA, W_hyp, b_hyp, W_sc, b_sc, eiB, eB, ew);

  // ---- layer 1 ----
  k_gcn_fused<KP0, true><<<BG, 1024, 0, stream>>>(eiB, E1, eB, W_gcn + D * D, b_gcn + D, ew, root + D, x, xs);
  k_hyper_sort<KP0, KP1, E2><<<BG, 1024, 0, stream>>>(eiB, E1, eB, W_hyp + D * D, b_hyp + D, W_sc + D, b_sc + 1, eiA2, eA, ew);

  // ---- layer 2 ----
  k_gcn_fused<KP1, true><<<BG, 1024, 0, stream>>>(eiA2, E2, eA, W_gcn + 2 * D * D, b_gcn + 2 * D, ew, root + 2 * D, x, xs);

  k_mlp<<<BG, 128, 0, stream>>>(xs, Wc1, bc1_, Wc2, bc2_, Wc3, bc3_, out);
}

// Round 20
// 220.486 us; speedup vs baseline: 1.2187x; 1.0174x over previous
//
#include <hip/hip_runtime.h>
#include <hip/hip_bf16.h>
#include <math.h>

constexpr int NTOT = 65536;
constexpr int D    = 128;
constexpr int BG   = 256;
constexpr int E0 = 131072, E1 = 104960, E2 = 83968;
constexpr int EG0 = 512;
constexpr int KP0 = 410, KP1 = 328;
constexpr int ESP = 136;                     // padded ES row stride (bf16)

typedef __bf16 bf16x8 __attribute__((ext_vector_type(8)));
typedef __bf16 bf16x4 __attribute__((ext_vector_type(4)));
typedef __bf16 bf16x2 __attribute__((ext_vector_type(2)));
typedef float  f32x4  __attribute__((ext_vector_type(4)));

__device__ __forceinline__ float2 tof2(bf16x2 v) {
  return make_float2((float)v[0], (float)v[1]);
}
__device__ __forceinline__ bf16x2 tob2(float ax, float ay) {
  bf16x2 r; r[0] = (__bf16)ax; r[1] = (__bf16)ay; return r;
}

// ---------- embeddings (f32 tables -> bf16 activations) ----------
__global__ __launch_bounds__(256) void k_embed_x(const int* __restrict__ xi,
                                                 const float* __restrict__ tab,
                                                 __bf16* __restrict__ x) {
  int t = blockIdx.x * 256 + threadIdx.x;      // NTOT*32 threads
  int v = t >> 5, q = (t & 31) << 2;
  float4 s = {0.f, 0.f, 0.f, 0.f};
#pragma unroll
  for (int j = 0; j < 9; ++j) {
    int r = xi[v * 9 + j];
    float4 a = *(const float4*)&tab[r * D + q];
    s.x += a.x; s.y += a.y; s.z += a.z; s.w += a.w;
  }
  bf16x4 o; o[0] = (__bf16)s.x; o[1] = (__bf16)s.y; o[2] = (__bf16)s.z; o[3] = (__bf16)s.w;
  *(bf16x4*)&x[(size_t)v * D + q] = o;
}

__global__ __launch_bounds__(256) void k_embed_e(const int* __restrict__ bi,
                                                 const float* __restrict__ tab,
                                                 __bf16* __restrict__ e) {
  int t = blockIdx.x * 256 + threadIdx.x;      // E0*32 threads
  int i = t >> 5, q = (t & 31) << 2;
  float4 s = {0.f, 0.f, 0.f, 0.f};
#pragma unroll
  for (int j = 0; j < 3; ++j) {
    int r = bi[i * 3 + j];
    float4 a = *(const float4*)&tab[r * D + q];
    s.x += a.x; s.y += a.y; s.z += a.z; s.w += a.w;
  }
  bf16x4 o; o[0] = (__bf16)s.x; o[1] = (__bf16)s.y; o[2] = (__bf16)s.z; o[3] = (__bf16)s.w;
  *(bf16x4*)&e[(size_t)i * D + q] = o;
}

// ---------- MEGA GCN layer: fused h = x@Wg + b (MFMA into LDS) + CSR message
//            passing + finalize + in-place x update + readout.
//            1 block/graph, 1024 thr (16 waves x 16 rows). ----------
template <int EG, bool HAS_EW>
__global__ __launch_bounds__(1024, 4) void k_gcn_fused(const int* __restrict__ ei, int E,
                                                       const __bf16* __restrict__ e,
                                                       const float* __restrict__ Wg,
                                                       const float* __restrict__ bg,
                                                       const float* __restrict__ ew,
                                                       const float* __restrict__ root,
                                                       __bf16* __restrict__ x,
                                                       float* __restrict__ xs) {
  constexpr int NW = 16;
  __shared__ bf16x8 Wl[4][8][64];             // 32 KB W fragments
  __shared__ __bf16 hl[256 * 128];            // 64 KB h tile
  __shared__ int   pke[EG];
  __shared__ float coef[EG];
  __shared__ int   cnts[256];
  __shared__ int   cntd[256];
  __shared__ int   off[257];
  __shared__ int   cur[256];
  __shared__ int   wsum[4];
  __shared__ short adj[EG];
  __shared__ float redm[16 * 128], reds[16 * 128];   // 16 KB
  const int g = blockIdx.x;
  const int t = threadIdx.x, w = t >> 6, lane = t & 63;
  const bf16x2* eg2 = (const bf16x2*)e + (size_t)g * EG * 64 + lane;
  bf16x2* xg2 = (bf16x2*)x + (size_t)g * 256 * 64 + lane;

  if (t < 256) { cnts[t] = 0; cntd[t] = 0; }
  __syncthreads();

  // Phase 1: CSR counts + packed indices, and W fragment staging (independent)
  for (int j = t; j < EG; j += 1024) {
    int s = ei[g * EG + j] & 255, d = ei[E + g * EG + j] & 255;
    pke[j] = s | (d << 8);
    atomicAdd(&cnts[s], 1);
    atomicAdd(&cntd[d], 1);
  }
  {
    bf16x8* Wf = (bf16x8*)Wl;
    for (int q = t; q < 2048; q += 1024) {
      int ks = q >> 9, nt = (q >> 6) & 7, l = q & 63;
      int kk = ks * 32 + ((l >> 4) << 3);
      int nn = nt * 16 + (l & 15);
      const float* wp = Wg + (size_t)kk * 128 + nn;
      bf16x8 v;
#pragma unroll
      for (int b = 0; b < 8; ++b) v[b] = (__bf16)wp[(size_t)b * 128];
      Wf[q] = v;
    }
  }
  __syncthreads();

  // Phase 2a: MFMA h = x@Wg + bg for this graph's 256 rows -> LDS hl
  {
    const int r0 = w * 16 + (lane & 15);
    const __bf16* Ap = x + ((size_t)(g * 256 + r0)) * 128 + ((lane >> 4) << 3);
    bf16x8 af[4];
#pragma unroll
    for (int ks = 0; ks < 4; ++ks) af[ks] = *(const bf16x8*)(Ap + ks * 32);
    f32x4 acc[8] = {};
#pragma unroll
    for (int ks = 0; ks < 4; ++ks) {
#pragma unroll
      for (int nt = 0; nt < 8; ++nt) {
        acc[nt] = __builtin_amdgcn_mfma_f32_16x16x32_bf16(af[ks], Wl[ks][nt][lane], acc[nt], 0, 0, 0);
      }
    }
    const int lrow = w * 16 + ((lane >> 4) << 2);
    const int ocol = lane & 15;
#pragma unroll
    for (int nt = 0; nt < 8; ++nt) {
      float bb = bg[nt * 16 + ocol];
#pragma unroll
      for (int r = 0; r < 4; ++r)
        hl[(lrow + r) * 128 + nt * 16 + ocol] = (__bf16)(acc[nt][r] + bb);
    }
  }

  // Phase 2b: per-edge coefficient
  for (int j = t; j < EG; j += 1024) {
    int p = pke[j];
    int s = p & 255, d = (p >> 8) & 255;
    float c = rsqrtf(((float)cnts[s] + 1.f) * ((float)cnts[d] + 1.f));
    if (HAS_EW) c *= ew[g * EG + j];
    coef[j] = c;
  }

  // Phase 2c: wave-shuffle exclusive scan of cntd (2 barriers)
  {
    int v = 0;
    if (t < 256) {
      v = cntd[t];
#pragma unroll
      for (int d2 = 1; d2 < 64; d2 <<= 1) {
        int u = __shfl_up(v, d2);
        if (lane >= d2) v += u;
      }
      if (lane == 63) wsum[w] = v;
    }
    __syncthreads();
    if (t < 256) {
      int add = 0;
      if (w > 0) add += wsum[0];
      if (w > 1) add += wsum[1];
      if (w > 2) add += wsum[2];
      off[t + 1] = v + add;
      if (t == 0) off[0] = 0;
      cur[t] = v + add - cntd[t];
    }
    __syncthreads();
  }

  for (int j = t; j < EG; j += 1024) {
    int d = (pke[j] >> 8) & 255;
    int pos = atomicAdd(&cur[d], 1);
    adj[pos] = (short)j;
  }
  __syncthreads();

  // Phase 3: per-node accumulate (e global, h LDS) + finalize + x + readout
  const float rvx = root[2 * lane], rvy = root[2 * lane + 1];
  float2 mx = {-1e30f, -1e30f}, sm = {0.f, 0.f};
  for (int n = w; n < 256; n += NW) {
    float2 val = {0.f, 0.f};
    int b0 = off[n], b1 = off[n + 1];
    int k = b0;
    for (; k + 1 < b1; k += 2) {
      int j0 = adj[k], j1 = adj[k + 1];
      int s0 = pke[j0] & 255, s1 = pke[j1] & 255;
      float2 e0 = tof2(eg2[(size_t)j0 * 64]), e1 = tof2(eg2[(size_t)j1 * 64]);
      float2 h0 = tof2(*(const bf16x2*)&hl[s0 * 128 + 2 * lane]);
      float2 h1 = tof2(*(const bf16x2*)&hl[s1 * 128 + 2 * lane]);
      float c0 = coef[j0], c1 = coef[j1];
      val.x += c0 * fmaxf(h0.x + e0.x, 0.f) + c1 * fmaxf(h1.x + e1.x, 0.f);
      val.y += c0 * fmaxf(h0.y + e0.y, 0.f) + c1 * fmaxf(h1.y + e1.y, 0.f);
    }
    if (k < b1) {
      int j0 = adj[k];
      int s0 = pke[j0] & 255;
      float2 e0 = tof2(eg2[(size_t)j0 * 64]);
      float2 h0 = tof2(*(const bf16x2*)&hl[s0 * 128 + 2 * lane]);
      float c0 = coef[j0];
      val.x += c0 * fmaxf(h0.x + e0.x, 0.f);
      val.y += c0 * fmaxf(h0.y + e0.y, 0.f);
    }
    float inv = 1.f / ((float)cnts[n] + 1.f);
    float2 hv = tof2(*(const bf16x2*)&hl[n * 128 + 2 * lane]);
    float xvx = fmaxf(val.x + fmaxf(hv.x + rvx, 0.f) * inv, 0.f);
    float xvy = fmaxf(val.y + fmaxf(hv.y + rvy, 0.f) * inv, 0.f);
    xg2[(size_t)n * 64] = tob2(xvx, xvy);
    mx.x = fmaxf(mx.x, xvx); mx.y = fmaxf(mx.y, xvy);
    sm.x += xvx;             sm.y += xvy;
  }
  redm[w * 128 + 2 * lane]     = mx.x;
  redm[w * 128 + 2 * lane + 1] = mx.y;
  reds[w * 128 + 2 * lane]     = sm.x;
  reds[w * 128 + 2 * lane + 1] = sm.y;
  __syncthreads();

  if (t < 128) {
    float M = redm[t], S2 = reds[t];
#pragma unroll
    for (int k = 1; k < 16; ++k) {
      M = fmaxf(M, redm[k * 128 + t]);
      S2 += reds[k * 128 + t];
    }
    xs[g * 384 + t]       += M;
    xs[g * 384 + 128 + t] += S2 * (1.f / 256.f);
    xs[g * 384 + 256 + t] += S2;
  }
}

// ---------- MEGA hyperconv + top-k, zbuf-free (linearity: S = Esum @ Wh):
//            CSR + Esum accumulate (LDS, padded stride) + S-MFMA (in-place) +
//            z-MFMA with fused gather/eout/score + sort + compaction.
//            1 block/graph, 1024 thr. ----------
template <int EG, int KEEP, int ENEW>
__global__ __launch_bounds__(1024, 4) void k_hyper_sort(const int* __restrict__ ei, int E,
                                                        __bf16* __restrict__ e,   // in: e; out: eout (in place)
                                                        const float* __restrict__ Wh,
                                                        const float* __restrict__ bias,
                                                        const float* __restrict__ wsc,
                                                        const float* __restrict__ bsc,
                                                        int* __restrict__ ei_new,
                                                        __bf16* __restrict__ e_new,
                                                        float* __restrict__ ew) {
  constexpr int NW = 16;
  __shared__ bf16x8 Wl[4][8][64];             // 32 KB W fragments
  __shared__ __bf16 ES[256 * ESP];            // 68 KB: Esum, then S (padded stride)
  __shared__ int   pke[EG];
  __shared__ float as_[EG], ad_[EG], az_[EG];
  __shared__ float zsh[EG];
  __shared__ float Ssh[256];
  __shared__ int   cnt[256];
  __shared__ int   off[257];
  __shared__ int   cur[256];
  __shared__ int   wsum[4];
  __shared__ short adj[2 * EG];
  __shared__ float ls[512];
  __shared__ int   li[512];
  __shared__ int   sidx[512];
  const int g = blockIdx.x;
  const int t = threadIdx.x, w = t >> 6, lane = t & 63;
  const int hi = lane >> 4, lo = lane & 15;
  const bf16x2* eg2 = (const bf16x2*)e + (size_t)g * EG * 64 + lane;
  bf16x2* ES2 = (bf16x2*)ES;

  if (t < 256) { cnt[t] = 0; Ssh[t] = 0.f; }
  __syncthreads();

  // Phase 1: CSR counts + pke + W fragment staging
  for (int j = t; j < EG; j += 1024) {
    int s = ei[g * EG + j] & 255, d = ei[E + g * EG + j] & 255;
    pke[j] = s | (d << 8);
    atomicAdd(&cnt[s], 1);
    atomicAdd(&cnt[d], 1);
  }
  {
    bf16x8* Wf = (bf16x8*)Wl;
    for (int q = t; q < 2048; q += 1024) {
      int ks = q >> 9, nt = (q >> 6) & 7, l = q & 63;
      int kk = ks * 32 + ((l >> 4) << 3);
      int nn = nt * 16 + (l & 15);
      const float* wp = Wh + (size_t)kk * 128 + nn;
      bf16x8 v;
#pragma unroll
      for (int b = 0; b < 8; ++b) v[b] = (__bf16)wp[(size_t)b * 128];
      Wf[q] = v;
    }
  }
  __syncthreads();

  // Phase 2: per-edge gather constants
  for (int j = t; j < EG; j += 1024) {
    int p = pke[j];
    int s = p & 255, d = (p >> 8) & 255;
    int cs = cnt[s], cd = cnt[d];
    float bis  = (cs != 1) ? 1.f / (float)cs : 0.f;
    float bid_ = (cd != 1) ? 1.f / (float)cd : 0.f;
    float dinv = 1.f / (1.f + (cs != 1 ? 1.f : 0.f) + (cd != 1 ? 1.f : 0.f));
    as_[j] = dinv * bis;
    ad_[j] = dinv * bid_;
    az_[j] = dinv;
  }

  // wave-shuffle exclusive scan of cnt (2 barriers)
  {
    int v = 0;
    if (t < 256) {
      v = cnt[t];
#pragma unroll
      for (int d2 = 1; d2 < 64; d2 <<= 1) {
        int u = __shfl_up(v, d2);
        if (lane >= d2) v += u;
      }
      if (lane == 63) wsum[w] = v;
    }
    __syncthreads();
    if (t < 256) {
      int add = 0;
      if (w > 0) add += wsum[0];
      if (w > 1) add += wsum[1];
      if (w > 2) add += wsum[2];
      off[t + 1] = v + add;
      if (t == 0) off[0] = 0;
      cur[t] = v + add - cnt[t];
    }
    __syncthreads();
  }

  for (int j = t; j < EG; j += 1024) {
    int p = pke[j];
    int pos0 = atomicAdd(&cur[p & 255], 1);
    adj[pos0] = (short)j;
    int pos1 = atomicAdd(&cur[(p >> 8) & 255], 1);
    adj[pos1] = (short)j;
  }
  __syncthreads();

  // Phase 3: Esum[n] = sum of incident e rows (f32 regs, bf16 LDS store)
  for (int n = w; n < 256; n += NW) {
    float2 val = {0.f, 0.f};
    int b0 = off[n], b1 = off[n + 1];
    int k = b0;
    for (; k + 1 < b1; k += 2) {
      float2 a = tof2(eg2[(size_t)adj[k] * 64]);
      float2 b = tof2(eg2[(size_t)adj[k + 1] * 64]);
      val.x += a.x + b.x;
      val.y += a.y + b.y;
    }
    if (k < b1) {
      float2 a = tof2(eg2[(size_t)adj[k] * 64]);
      val.x += a.x; val.y += a.y;
    }
    ES2[n * (ESP / 2) + lane] = tob2(val.x, val.y);
  }
  __syncthreads();

  // Phase 4: S = Esum @ Wh (in-place in ES; each wave owns its 16-row tile)
  {
    const int mr = w * 16 + lo;
    const __bf16* Ep = ES + mr * ESP + (hi << 3);
    bf16x8 ef[4];
#pragma unroll
    for (int ks = 0; ks < 4; ++ks) ef[ks] = *(const bf16x8*)(Ep + ks * 32);
    f32x4 acc[8] = {};
#pragma unroll
    for (int ks = 0; ks < 4; ++ks) {
#pragma unroll
      for (int nt = 0; nt < 8; ++nt) {
        acc[nt] = __builtin_amdgcn_mfma_f32_16x16x32_bf16(ef[ks], Wl[ks][nt][lane], acc[nt], 0, 0, 0);
      }
    }
    const int lrow = w * 16 + (hi << 2);
#pragma unroll
    for (int nt = 0; nt < 8; ++nt) {
#pragma unroll
      for (int r = 0; r < 4; ++r)
        ES[(lrow + r) * ESP + nt * 16 + lo] = (__bf16)acc[nt][r];
    }
  }
  __syncthreads();

  // Phase 5: z = e @ Wh (MFMA, z stays in registers) + fused gather/eout/score
  {
    const int r0 = w * 32 + lo;
    const int r1 = r0 + 16;
    bf16x8 a0[4], a1[4];
    {
      bf16x8 zz = {};
      const __bf16* Ap0 = e + ((size_t)g * EG + r0) * 128 + (hi << 3);
      const __bf16* Ap1 = Ap0 + (size_t)16 * 128;
#pragma unroll
      for (int ks = 0; ks < 4; ++ks) {
        a0[ks] = (r0 < EG) ? *(const bf16x8*)(Ap0 + ks * 32) : zz;
        a1[ks] = (r1 < EG) ? *(const bf16x8*)(Ap1 + ks * 32) : zz;
      }
    }
    f32x4 acc0[8] = {}; f32x4 acc1[8] = {};
#pragma unroll
    for (int ks = 0; ks < 4; ++ks) {
#pragma unroll
      for (int nt = 0; nt < 8; ++nt) {
        bf16x8 b = Wl[ks][nt][lane];
        acc0[nt] = __builtin_amdgcn_mfma_f32_16x16x32_bf16(a0[ks], b, acc0[nt], 0, 0, 0);
        acc1[nt] = __builtin_amdgcn_mfma_f32_16x16x32_bf16(a1[ks], b, acc1[nt], 0, 0, 0);
      }
    }
    // epilogue: per-lane rows row0+r (acc0) and row1+r (acc1), col nt*16+lo
    const int row0 = w * 32 + (hi << 2);
    const int row1 = row0 + 16;
    float wv[8], bb[8];
#pragma unroll
    for (int nt = 0; nt < 8; ++nt) {
      wv[nt] = wsc[nt * 16 + lo];
      bb[nt] = bias[nt * 16 + lo];
    }
    float as0[4], ad0[4], az0[4], as1[4], ad1[4], az1[4];
    int ps0[4], pd0[4], ps1[4], pd1[4];
#pragma unroll
    for (int r = 0; r < 4; ++r) {
      int ra = row0 + r;
      if (ra < EG) {
        int p = pke[ra];
        ps0[r] = (p & 255) * ESP; pd0[r] = ((p >> 8) & 255) * ESP;
        as0[r] = as_[ra]; ad0[r] = ad_[ra]; az0[r] = az_[ra];
      } else { ps0[r] = 0; pd0[r] = 0; as0[r] = 0.f; ad0[r] = 0.f; az0[r] = 0.f; }
      int rb = row1 + r;
      if (rb < EG) {
        int p = pke[rb];
        ps1[r] = (p & 255) * ESP; pd1[r] = ((p >> 8) & 255) * ESP;
        as1[r] = as_[rb]; ad1[r] = ad_[rb]; az1[r] = az_[rb];
      } else { ps1[r] = 0; pd1[r] = 0; as1[r] = 0.f; ad1[r] = 0.f; az1[r] = 0.f; }
    }
    float sp0[4] = {0.f, 0.f, 0.f, 0.f};
    float sp1[4] = {0.f, 0.f, 0.f, 0.f};
#pragma unroll
    for (int nt = 0; nt < 8; ++nt) {
      int col = nt * 16 + lo;
#pragma unroll
      for (int r = 0; r < 4; ++r) {
        if (row0 + r < EG) {
          float o = fmaxf(as0[r] * (float)ES[ps0[r] + col] + ad0[r] * (float)ES[pd0[r] + col]
                          + az0[r] * acc0[nt][r] + bb[nt], 0.f);
          e[((size_t)g * EG + row0 + r) * 128 + col] = (__bf16)o;
          sp0[r] += o * wv[nt];
        }
        if (row1 + r < EG) {
          float o = fmaxf(as1[r] * (float)ES[ps1[r] + col] + ad1[r] * (float)ES[pd1[r] + col]
                          + az1[r] * acc1[nt][r] + bb[nt], 0.f);
          e[((size_t)g * EG + row1 + r) * 128 + col] = (__bf16)o;
          sp1[r] += o * wv[nt];
        }
      }
    }
    // reduce score partials across the 16-lane (lo) group
#pragma unroll
    for (int offs = 1; offs < 16; offs <<= 1) {
#pragma unroll
      for (int r = 0; r < 4; ++r) {
        sp0[r] += __shfl_xor(sp0[r], offs);
        sp1[r] += __shfl_xor(sp1[r], offs);
      }
    }
    if (lo == 0) {
#pragma unroll
      for (int r = 0; r < 4; ++r) {
        if (row0 + r < EG) zsh[row0 + r] = sp0[r];
        if (row1 + r < EG) zsh[row1 + r] = sp1[r];
      }
    }
  }
  __syncthreads();

  // Phase 6: scalar hyperconv on scores
  if (t < EG) {
    float v = zsh[t];
    atomicAdd(&Ssh[pke[t] & 255], v);
    atomicAdd(&Ssh[(pke[t] >> 8) & 255], v);
  }
  __syncthreads();

  // Phase 7: score finalize + bitonic sort
  float sc = -INFINITY; int idx = 0x7FFFFFFF;
  if (t < EG) {
    int p = pke[t];
    int sn = p & 255, dn = (p >> 8) & 255;
    sc = tanhf(as_[t] * Ssh[sn] + ad_[t] * Ssh[dn] + az_[t] * zsh[t] + bsc[0]);
    idx = t;
  }
#pragma unroll
  for (int k = 2; k <= 512; k <<= 1) {
#pragma unroll
    for (int j = k >> 1; j > 0; j >>= 1) {
      if (j < 64) {
        if (t < 512) {
          float ps = __shfl_xor(sc, j);
          int   pi = __shfl_xor(idx, j);
          bool ownBetter = (sc > ps) || (sc == ps && idx < pi);
          bool lower = ((t & j) == 0);
          bool desc = ((t & k) == 0);
          bool keep = desc ? (lower ? ownBetter : !ownBetter)
                           : (lower ? !ownBetter : ownBetter);
          if (!keep) { sc = ps; idx = pi; }
        }
      } else {
        if (t < 512) { ls[t] = sc; li[t] = idx; }
        __syncthreads();
        if (t < 512) {
          float ps = ls[t ^ j];
          int   pi = li[t ^ j];
          bool ownBetter = (sc > ps) || (sc == ps && idx < pi);
          bool lower = ((t & j) == 0);
          bool desc = ((t & k) == 0);
          bool keep = desc ? (lower ? ownBetter : !ownBetter)
                           : (lower ? !ownBetter : ownBetter);
          if (!keep) { sc = ps; idx = pi; }
        }
        __syncthreads();
      }
    }
  }

  if (t < 512) sidx[t] = idx;
  if (t < KEEP) {
    int oldp = g * EG + idx;
    int newp = g * KEEP + t;
    ei_new[newp]        = ei[oldp];
    ei_new[ENEW + newp] = ei[E + oldp];
    ew[newp] = fminf(fmaxf(sc, 0.f), 1.f);
  }
  __syncthreads();

  // Phase 8: compaction (reads eout rows this block wrote; barrier-ordered)
  const float4* src = (const float4*)e;
  float4* dst = (float4*)e_new;
  for (int q = t; q < KEEP * 16; q += 1024) {
    int j2 = q >> 4, c = q & 15;
    dst[((size_t)g * KEEP + j2) * 16 + c] = src[((size_t)g * EG + sidx[j2]) * 16 + c];
  }
}

// ---------- final MLP ----------
__global__ __launch_bounds__(128) void k_mlp(const float* __restrict__ xs,
                                             const float* __restrict__ Wc1, const float* __restrict__ bc1,
                                             const float* __restrict__ Wc2, const float* __restrict__ bc2,
                                             const float* __restrict__ Wc3, const float* __restrict__ bc3,
                                             float* __restrict__ out) {
  __shared__ float row[384];
  __shared__ float h1[128];
  __shared__ float h2[64];
  int g = blockIdx.x, t = threadIdx.x;
  for (int i = t; i < 384; i += 128) row[i] = xs[g * 384 + i];
  __syncthreads();
  float a = bc1[t];
  for (int k = 0; k < 384; ++k) a += row[k] * Wc1[k * 128 + t];
  h1[t] = fmaxf(a, 0.f);
  __syncthreads();
  if (t < 64) {
    float b = bc2[t];
    for (int k = 0; k < 128; ++k) b += h1[k] * Wc2[k * 64 + t];
    h2[t] = fmaxf(b, 0.f);
  }
  __syncthreads();
  float o = bc3[t];
  for (int k = 0; k < 64; ++k) o += h2[k] * Wc3[k * 128 + t];
  out[g * 128 + t] = o;
}

extern "C" void kernel_launch(void* const* d_in, const int* in_sizes, int n_in,
                              void* d_out, int out_size, void* d_ws, size_t ws_size,
                              hipStream_t stream) {
  (void)in_sizes; (void)n_in; (void)out_size; (void)ws_size;
  const int*   x_idx  = (const int*)d_in[0];
  const int*   b_idx  = (const int*)d_in[1];
  const int*   ei0    = (const int*)d_in[2];
  const float* atom_t = (const float*)d_in[4];
  const float* bond_t = (const float*)d_in[5];
  const float* W_gcn  = (const float*)d_in[6];
  const float* b_gcn  = (const float*)d_in[7];
  const float* root   = (const float*)d_in[8];
  const float* W_hyp  = (const float*)d_in[9];
  const float* b_hyp  = (const float*)d_in[10];
  const float* W_sc   = (const float*)d_in[11];
  const float* b_sc   = (const float*)d_in[12];
  const float* Wc1    = (const float*)d_in[13];
  const float* bc1_   = (const float*)d_in[14];
  const float* Wc2    = (const float*)d_in[15];
  const float* bc2_   = (const float*)d_in[16];
  const float* Wc3    = (const float*)d_in[17];
  const float* bc3_   = (const float*)d_in[18];
  float* out = (float*)d_out;

  // workspace layout: bf16 activations first, then f32 scalars
  __bf16* x    = (__bf16*)d_ws;
  __bf16* eA   = x    + (size_t)NTOT * D;
  __bf16* eB   = eA   + (size_t)E0 * D;
  float* ew  = (float*)(eB + (size_t)E0 * D);
  float* xs  = ew + E0;
  int*   eiB  = (int*)(xs + BG * 384);
  int*   eiA2 = eiB + 2 * E0;

  hipMemsetAsync(xs, 0, BG * 384 * 4, stream);
  k_embed_x<<<NTOT * 32 / 256, 256, 0, stream>>>(x_idx, atom_t, x);
  k_embed_e<<<E0 * 32 / 256, 256, 0, stream>>>(b_idx, bond_t, eA);

  // ---- layer 0 ----
  k_gcn_fused<EG0, false><<<BG, 1024, 0, stream>>>(ei0, E0, eA, W_gcn, b_gcn, nullptr, root, x, xs);
  k_hyper_sort<EG0, KP0, E1><<<BG, 1024, 0, stream>>>(ei0, E0, eA, W_hyp, b_hyp, W_sc, b_sc, eiB, eB, ew);

  // ---- layer 1 ----
  k_gcn_fused<KP0, true><<<BG, 1024, 0, stream>>>(eiB, E1, eB, W_gcn + D * D, b_gcn + D, ew, root + D, x, xs);
  k_hyper_sort<KP0, KP1, E2><<<BG, 1024, 0, stream>>>(eiB, E1, eB, W_hyp + D * D, b_hyp + D, W_sc + D, b_sc + 1, eiA2, eA, ew);

  // ---- layer 2 ----
  k_gcn_fused<KP1, true><<<BG, 1024, 0, stream>>>(eiA2, E2, eA, W_gcn + 2 * D * D, b_gcn + 2 * D, ew, root + 2 * D, x, xs);

  k_mlp<<<BG, 128, 0, stream>>>(xs, Wc1, bc1_, Wc2, bc2_, Wc3, bc3_, out);
}